// Round 8
// baseline (4373.195 us; speedup 1.0000x reference)
//
#include <hip/hip_runtime.h>
#include <hip/hip_bf16.h>

typedef __hip_bfloat16 bf16;
typedef __attribute__((ext_vector_type(8))) short s16x8;
typedef __attribute__((ext_vector_type(4))) float f32x4;
typedef __attribute__((ext_vector_type(2))) float f32x2;

#define B_TOT 1024
#define T_LEN 256
#define H_DIM 256
#define PRED_LEN 16

__device__ __forceinline__ float b2f(short u) {
  union { unsigned int i; float f; } c;
  c.i = ((unsigned int)(unsigned short)u) << 16;
  return c.f;
}
__device__ __forceinline__ float fsig(float x) {
  return __builtin_amdgcn_rcpf(1.f + __expf(-x));
}
__device__ __forceinline__ float ftanh(float x) {
  return 1.f - 2.f * __builtin_amdgcn_rcpf(1.f + __expf(2.f * x));
}
__device__ __forceinline__ f32x4 mfma16(s16x8 a, s16x8 b, f32x4 c) {
  return __builtin_amdgcn_mfma_f32_16x16x32_bf16(a, b, c, 0, 0, 0);
}
template <int HI>
__device__ __forceinline__ f32x2 fp8pk2f(unsigned int pk) {
  return __builtin_amdgcn_cvt_pk_f32_fp8(pk, HI);
}
__device__ __forceinline__ unsigned char f2fp8(float v) {
  return (unsigned char)(__builtin_amdgcn_cvt_pk_fp8_f32(v, v, 0, 0) & 0xff);
}
__device__ __forceinline__ uint2 pk8fp8(s16x8 hv) {
  unsigned int lo = 0, hi = 0;
  lo = __builtin_amdgcn_cvt_pk_fp8_f32(b2f(hv[0]), b2f(hv[1]), lo, 0);
  lo = __builtin_amdgcn_cvt_pk_fp8_f32(b2f(hv[2]), b2f(hv[3]), lo, 1);
  hi = __builtin_amdgcn_cvt_pk_fp8_f32(b2f(hv[4]), b2f(hv[5]), hi, 0);
  hi = __builtin_amdgcn_cvt_pk_fp8_f32(b2f(hv[6]), b2f(hv[7]), hi, 1);
  uint2 w; w.x = lo; w.y = hi; return w;
}

// ---------- Kernel 0: pack fp32 weights -> bf16 ws layouts ------------------
__global__ __launch_bounds__(256) void convert_kernel(
    const float* __restrict__ eWhh, const float* __restrict__ Wt,
    const float* __restrict__ dWhh, const float* __restrict__ dWih,
    bf16* __restrict__ encWF, bf16* __restrict__ wtEncF,
    bf16* __restrict__ wtDec, bf16* __restrict__ whhD, bf16* __restrict__ wihPD)
{
  int i = blockIdx.x*256 + threadIdx.x;
  if (i < 24576) {           // encWF fragment slots
    int l = i & 63, kc = (i>>6)&7, tile = i>>9;
    int j = tile*16 + (l&15);
    int k = kc*32 + ((l>>4)&3)*8;
    #pragma unroll
    for (int e = 0; e < 8; ++e)
      encWF[i*8+e] = __float2bfloat16(eWhh[j*256 + k + e]);
  } else if (i < 32768) {    // wtEncF fragment slots
    int s = i - 24576;
    int l = s & 63, kc = (s>>6)&7, tile = s>>9;
    int j = tile*16 + (l&15);
    int k = kc*32 + ((l>>4)&3)*8;
    #pragma unroll
    for (int e = 0; e < 8; ++e)
      wtEncF[s*8+e] = __float2bfloat16(Wt[j*512 + 256 + k + e]);
  }
  if (i < 768*288) {
    int g = i / 288, k = i - g*288;
    wihPD[i] = __float2bfloat16((k < 265) ? dWih[g*265 + k] : 0.f);
  }
  if (i < 256*256) {
    int g = i >> 8, k = i & 255;
    wtDec[i] = __float2bfloat16(Wt[g*512 + k]);
  }
  if (i < 768*256) whhD[i] = __float2bfloat16(dWhh[i]);
}

// ---------- Kernel 1: agent attention (unchanged) --------------------------
__global__ __launch_bounds__(256) void agent_attn_kernel(
    const float* __restrict__ x, const float* __restrict__ Wa,
    const float* __restrict__ ba, const float* __restrict__ va,
    float* __restrict__ treprs)
{
  __shared__ float w0[256], w1[256], w2[256], baL[256], vaL[256];
  int tid = threadIdx.x;
  w0[tid] = Wa[tid*3+0];
  w1[tid] = Wa[tid*3+1];
  w2[tid] = Wa[tid*3+2];
  baL[tid] = ba[tid];
  vaL[tid] = va[tid];
  __syncthreads();
  long idx = (long)blockIdx.x * 256 + tid;
  float xa[9];
  #pragma unroll
  for (int i = 0; i < 9; ++i) xa[i] = x[idx*9 + i];
  float s0 = 0.f, s1 = 0.f, s2 = 0.f;
  for (int h = 0; h < 256; ++h) {
    float a0 = w0[h], a1 = w1[h], a2 = w2[h], bb = baL[h], vv = vaL[h];
    s0 += ftanh(a0*xa[0] + a1*xa[1] + a2*xa[2] + bb) * vv;
    s1 += ftanh(a0*xa[3] + a1*xa[4] + a2*xa[5] + bb) * vv;
    s2 += ftanh(a0*xa[6] + a1*xa[7] + a2*xa[8] + bb) * vv;
  }
  float mx = fmaxf(s0, fmaxf(s1, s2));
  float e0 = __expf(s0-mx), e1 = __expf(s1-mx), e2 = __expf(s2-mx);
  float inv = __builtin_amdgcn_rcpf(e0+e1+e2);
  e0 *= inv; e1 *= inv; e2 *= inv;
  treprs[idx*3+0] = e0*xa[0] + e1*xa[3] + e2*xa[6];
  treprs[idx*3+1] = e0*xa[1] + e1*xa[4] + e2*xa[7];
  treprs[idx*3+2] = e0*xa[2] + e1*xa[5] + e2*xa[8];
}

// ---------- Kernel 2: weight-stationary encoder, B_wg=4, 256 wgs -----------
__global__ __launch_bounds__(512, 2) void encoder_kernel(
    const bf16* __restrict__ encWF, const float* __restrict__ eWih,
    const float* __restrict__ ebih, const float* __restrict__ ebhh,
    const float* __restrict__ treprs, unsigned char* __restrict__ eo8,
    float* __restrict__ h_enc)
{
  __shared__ __align__(16) bf16  hbF[8*64*8];      // frag-linear h tile (8 KB)
  __shared__ __align__(16) bf16  hb_lin[4*264];    // row-linear h for eo8 pack
  __shared__ __align__(16) float hf[4*260];        // fp32 recurrent state
  __shared__ __align__(16) f32x4 wihAll[768];      // (w0,w1,w2, bias)
  __shared__ float bhhnL[256];
  __shared__ float xtL[2][16];

  const int tid = threadIdx.x;
  const int b0 = blockIdx.x * 4;

  for (int i = tid; i < 768; i += 512) {
    f32x4 w;
    w.x = eWih[i*3+0]; w.y = eWih[i*3+1]; w.z = eWih[i*3+2];
    w.w = (i < 512) ? (ebih[i] + ebhh[i]) : ebih[i];
    wihAll[i] = w;
    if (i >= 512) bhhnL[i-512] = ebhh[i];
  }
  for (int i = tid; i < 4*260; i += 512) hf[i] = 0.f;
  for (int i = tid; i < 8*64*8; i += 512) hbF[i] = __float2bfloat16(0.f);
  for (int i = tid; i < 4*264; i += 512) hb_lin[i] = __float2bfloat16(0.f);
  if (tid < 16) {
    int b = tid >> 2, f = tid & 3;
    xtL[0][tid] = (f < 3) ? treprs[((long)(b0+b)*T_LEN + 0)*3 + f] : 0.f;
  }

  const int lane = tid & 63;
  const int wv   = tid >> 6;
  const int nrow = lane & 15;
  const int quad = lane >> 4;

  s16x8 wf[32];
  #pragma unroll
  for (int u = 0; u < 4; ++u) {
    int tile = (u < 2) ? (2*wv + u) : (16 + 2*wv + (u-2));
    #pragma unroll
    for (int kc = 0; kc < 8; ++kc)
      wf[u*8+kc] = *(const s16x8*)(encWF + (((long)tile*8 + kc)*64 + lane)*8);
  }
  __syncthreads();

  for (int t = 0; t < 256; ++t) {
    s16x8 afr[8];
    #pragma unroll
    for (int kc = 0; kc < 8; ++kc)
      afr[kc] = *(const s16x8*)&hbF[(kc*64 + lane)*8];
    if (t >= 1 && tid < 128) {
      int b = tid >> 5, seg = tid & 31;
      s16x8 hv = *(const s16x8*)&hb_lin[b*264 + seg*8];
      *(uint2*)(eo8 + ((long)(b0+b)*T_LEN + (t-1))*H_DIM + seg*8) = pk8fp8(hv);
    }
    __syncthreads();

    f32x4 acc[6] = {};
    #pragma unroll
    for (int kc = 0; kc < 8; ++kc) {
      #pragma unroll
      for (int u = 0; u < 4; ++u)
        acc[u] = mfma16(afr[kc], wf[u*8+kc], acc[u]);
    }
    #pragma unroll
    for (int half = 0; half < 2; ++half) {
      s16x8 nf[8];
      #pragma unroll
      for (int kc = 0; kc < 8; ++kc)
        nf[kc] = *(const s16x8*)(encWF + (((long)(32 + 2*wv + half)*8 + kc)*64 + lane)*8);
      #pragma unroll
      for (int kc = 0; kc < 8; ++kc)
        acc[4+half] = mfma16(afr[kc], nf[kc], acc[4+half]);
    }

    if (t < 255 && tid < 16) {
      int b = tid >> 2, f = tid & 3;
      xtL[(t+1)&1][tid] = (f < 3) ? treprs[((long)(b0+b)*T_LEN + (t+1))*3 + f] : 0.f;
    }

    {
      float x0 = xtL[t & 1][quad*4+0];
      float x1 = xtL[t & 1][quad*4+1];
      float x2 = xtL[t & 1][quad*4+2];
      #pragma unroll
      for (int c = 0; c < 2; ++c) {
        int j = wv*32 + c*16 + nrow;
        f32x4 wr = wihAll[j];
        f32x4 wz = wihAll[256+j];
        f32x4 wn = wihAll[512+j];
        float rg = fsig(wr.x*x0 + wr.y*x1 + wr.z*x2 + wr.w + acc[c][0]);
        float zg = fsig(wz.x*x0 + wz.y*x1 + wz.z*x2 + wz.w + acc[2+c][0]);
        float ng = ftanh(wn.x*x0 + wn.y*x1 + wn.z*x2 + wn.w
                         + rg*(acc[4+c][0] + bhhnL[j]));
        float hold = hf[quad*260 + j];
        float hnew = ng + zg*(hold - ng);
        hf[quad*260 + j] = hnew;
        bf16 hv = __float2bfloat16(hnew);
        hb_lin[quad*264 + j] = hv;
        hbF[((j>>5)*64 + ((j>>3)&3)*16 + 4*quad)*8 + (j&7)] = hv;
      }
    }
    __syncthreads();
  }

  if (tid < 128) {
    int b = tid >> 5, seg = tid & 31;
    s16x8 hv = *(const s16x8*)&hb_lin[b*264 + seg*8];
    *(uint2*)(eo8 + ((long)(b0+b)*T_LEN + 255)*H_DIM + seg*8) = pk8fp8(hv);
  }
  for (int i = tid; i < 4*256; i += 512) {
    int m = i >> 8, j = i & 255;
    h_enc[(long)(b0+m)*H_DIM + j] = hf[m*260 + j];
  }
}

// ---------- Kernel 3: enc_proj GEMM (unchanged) ----------------------------
__global__ __launch_bounds__(256) void proj_kernel(
    const unsigned char* __restrict__ eo8, const bf16* __restrict__ wtEncF,
    unsigned char* __restrict__ ep8)
{
  __shared__ __align__(16) bf16 Asm[4*8*64*8];
  __shared__ __align__(16) unsigned char Cst[64*256];
  const int tid = threadIdx.x;
  const long R0 = (long)blockIdx.x * 64;
  const int lane = tid & 63, wv = tid >> 6;
  const int nrow = lane & 15, quad = lane >> 4;

  #pragma unroll
  for (int s8 = 0; s8 < 8; ++s8) {
    int s = tid + s8*256;
    int l = s & 63, kc = (s>>6)&7, at = s>>9;
    int m = at*16 + (l&15), k = kc*32 + ((l>>4)&3)*8;
    uint2 v = *(const uint2*)(eo8 + (R0+m)*H_DIM + k);
    s16x8 o; f32x2 d;
    d = fp8pk2f<0>(v.x); o[0] = __bfloat16_as_short(__float2bfloat16(d.x)); o[1] = __bfloat16_as_short(__float2bfloat16(d.y));
    d = fp8pk2f<1>(v.x); o[2] = __bfloat16_as_short(__float2bfloat16(d.x)); o[3] = __bfloat16_as_short(__float2bfloat16(d.y));
    d = fp8pk2f<0>(v.y); o[4] = __bfloat16_as_short(__float2bfloat16(d.x)); o[5] = __bfloat16_as_short(__float2bfloat16(d.y));
    d = fp8pk2f<1>(v.y); o[6] = __bfloat16_as_short(__float2bfloat16(d.x)); o[7] = __bfloat16_as_short(__float2bfloat16(d.y));
    *(s16x8*)&Asm[s*8] = o;
  }
  __syncthreads();

  f32x4 acc[16];
  #pragma unroll
  for (int n = 0; n < 16; ++n) acc[n] = f32x4{0.f,0.f,0.f,0.f};
  #pragma unroll
  for (int kc = 0; kc < 8; ++kc) {
    s16x8 a = *(const s16x8*)&Asm[((wv*8 + kc)*64 + lane)*8];
    #pragma unroll
    for (int nt = 0; nt < 16; ++nt) {
      s16x8 b = *(const s16x8*)(wtEncF + ((nt*8 + kc)*64 + lane)*8);
      acc[nt] = mfma16(a, b, acc[nt]);
    }
  }
  #pragma unroll
  for (int nt = 0; nt < 16; ++nt)
    #pragma unroll
    for (int r = 0; r < 4; ++r)
      Cst[(wv*16 + quad*4 + r)*256 + nt*16 + nrow] = f2fp8(acc[nt][r]);
  __syncthreads();

  {
    int row = tid >> 2, seg = tid & 3;
    #pragma unroll
    for (int p = 0; p < 4; ++p)
      *(uint4*)(ep8 + (R0+row)*H_DIM + seg*64 + p*16) =
          *(const uint4*)&Cst[row*256 + seg*64 + p*16];
  }
}

// ---------- Kernel 4: decoder, B_wg=2, 512 wgs; NO VGPR cap ----------------
__global__ __launch_bounds__(512) void decoder_kernel(
    const float* __restrict__ x, const bf16* __restrict__ wtDec,
    const float* __restrict__ bt, const float* __restrict__ vt,
    const bf16* __restrict__ wihPD, const bf16* __restrict__ whhD,
    const float* __restrict__ dbih, const float* __restrict__ dbhh,
    const float* __restrict__ Wfc, const float* __restrict__ bfc,
    const unsigned char* __restrict__ eo8, const unsigned char* __restrict__ ep8,
    const float* __restrict__ h_enc, float* __restrict__ out)
{
  __shared__ __align__(16) float hfL[2*260];
  __shared__ __align__(16) bf16  hbL[16*264];   // rows 2..15 stay zero
  __shared__ __align__(16) float qL[2*260];
  __shared__ float twL[2*260];
  __shared__ __align__(16) bf16  inpb[16*296];
  __shared__ __align__(16) float vtL[256];
  __shared__ float btL[256];
  __shared__ float bihL[768];
  __shared__ float bhhL[768];
  __shared__ __align__(16) float WfcL[9*260];
  __shared__ float bfcL[9];
  __shared__ float decin[24];
  __shared__ __align__(16) float scratch[4096];

  const int tid = threadIdx.x;
  const int b0 = blockIdx.x * 2;

  for (int i = tid; i < 256; i += 512) { vtL[i] = vt[i]; btL[i] = bt[i]; }
  for (int i = tid; i < 768; i += 512) { bihL[i] = dbih[i]; bhhL[i] = dbhh[i]; }
  for (int i = tid; i < 9*256; i += 512) { int o = i >> 8, k = i & 255; WfcL[o*260+k] = Wfc[i]; }
  if (tid < 9) bfcL[tid] = bfc[tid];
  for (int i = tid; i < 2*260; i += 512) { int m = i/260, j = i - m*260; hfL[i] = (j < 256) ? h_enc[(long)(b0+m)*H_DIM + j] : 0.f; }
  for (int i = tid; i < 16*264; i += 512) hbL[i] = __float2bfloat16(0.f);
  for (int i = tid; i < 16*296; i += 512) inpb[i] = __float2bfloat16(0.f);
  if (tid < 18) { int b = tid/9, o = tid - b*9; decin[b*12+o] = x[((long)(b0+b)*T_LEN + (T_LEN-1))*9 + o]; }
  __syncthreads();

  const int lane = tid & 63;
  const int wv   = tid >> 6;
  const int nrow = lane & 15;
  const int quad = lane >> 4;

  const bf16* qptr[2];
  #pragma unroll
  for (int u = 0; u < 2; ++u) {
    int g = wv*32 + u*16 + nrow;
    qptr[u] = wtDec + (long)g*H_DIM + quad*8;
  }
  const bf16* giptr[6];
  const bf16* ghptr[6];
  #pragma unroll
  for (int u = 0; u < 6; ++u) {
    int tile = (u < 2) ? (2*wv + u) : (u < 4) ? (16 + 2*wv + (u-2)) : (32 + 2*wv + (u-4));
    int g = tile*16 + nrow;
    giptr[u] = wihPD + (long)g*288 + quad*8;
    ghptr[u] = whhD + (long)g*H_DIM + quad*8;
  }

  for (int s = 0; s < PRED_LEN; ++s) {
    // 1. stage h (bf16) for MFMA A-operand
    {
      int m = tid >> 8, j = tid & 255;
      hbL[m*264 + j] = __float2bfloat16(hfL[m*260 + j]);
    }
    __syncthreads();

    // 2. q = h @ Wt_dec^T + bt
    {
      f32x4 qacc[2] = {};
      #pragma unroll
      for (int kc = 0; kc < 8; ++kc) {
        s16x8 a = *(const s16x8*)&hbL[nrow*264 + kc*32 + quad*8];
        #pragma unroll
        for (int u = 0; u < 2; ++u) {
          s16x8 bw = *(const s16x8*)(qptr[u] + kc*32);
          qacc[u] = mfma16(a, bw, qacc[u]);
        }
      }
      if (quad == 0) {
        #pragma unroll
        for (int u = 0; u < 2; ++u) {
          int g = wv*32 + u*16 + nrow;
          #pragma unroll
          for (int r = 0; r < 2; ++r)
            qL[r*260 + g] = qacc[u][r] + btL[g];
        }
      }
    }
    __syncthreads();

    // 3. scores: thread (bb,t); 4-way split accumulator
    {
      int bb = tid >> 8, t = tid & 255;
      const uint4* ep4 = (const uint4*)(ep8 + ((long)(b0+bb)*T_LEN + t)*H_DIM);
      const float* qrow = &qL[bb*260];
      float s0 = 0.f, s1 = 0.f, s2 = 0.f, s3 = 0.f;
      #pragma unroll
      for (int kc = 0; kc < 16; ++kc) {
        uint4 pv = ep4[kc];
        float vals[16];
        f32x2 d;
        d = fp8pk2f<0>(pv.x); vals[0]=d.x;  vals[1]=d.y;
        d = fp8pk2f<1>(pv.x); vals[2]=d.x;  vals[3]=d.y;
        d = fp8pk2f<0>(pv.y); vals[4]=d.x;  vals[5]=d.y;
        d = fp8pk2f<1>(pv.y); vals[6]=d.x;  vals[7]=d.y;
        d = fp8pk2f<0>(pv.z); vals[8]=d.x;  vals[9]=d.y;
        d = fp8pk2f<1>(pv.z); vals[10]=d.x; vals[11]=d.y;
        d = fp8pk2f<0>(pv.w); vals[12]=d.x; vals[13]=d.y;
        d = fp8pk2f<1>(pv.w); vals[14]=d.x; vals[15]=d.y;
        #pragma unroll
        for (int j = 0; j < 4; ++j) {
          s0 += ftanh(vals[4*j+0] + qrow[kc*16+4*j+0]) * vtL[kc*16+4*j+0];
          s1 += ftanh(vals[4*j+1] + qrow[kc*16+4*j+1]) * vtL[kc*16+4*j+1];
          s2 += ftanh(vals[4*j+2] + qrow[kc*16+4*j+2]) * vtL[kc*16+4*j+2];
          s3 += ftanh(vals[4*j+3] + qrow[kc*16+4*j+3]) * vtL[kc*16+4*j+3];
        }
      }
      scratch[bb*256 + t] = (s0+s1) + (s2+s3);
    }
    __syncthreads();

    // 4. softmax over t
    if (wv < 2) {
      float v4[4];
      float mx = -1e30f;
      #pragma unroll
      for (int i = 0; i < 4; ++i) { v4[i] = scratch[wv*256 + lane + 64*i]; mx = fmaxf(mx, v4[i]); }
      #pragma unroll
      for (int off = 1; off < 64; off <<= 1) mx = fmaxf(mx, __shfl_xor(mx, off));
      float sum = 0.f;
      #pragma unroll
      for (int i = 0; i < 4; ++i) { v4[i] = __expf(v4[i] - mx); sum += v4[i]; }
      #pragma unroll
      for (int off = 1; off < 64; off <<= 1) sum += __shfl_xor(sum, off);
      float inv = __builtin_amdgcn_rcpf(sum);
      #pragma unroll
      for (int i = 0; i < 4; ++i) twL[wv*260 + lane + 64*i] = v4[i] * inv;
    }
    __syncthreads();

    // 5. context
    {
      int tq = tid >> 6, b = (tid >> 5) & 1, h8 = (tid & 31) * 8;
      const unsigned char* eob = eo8 + ((long)(b0+b)*T_LEN + tq*32)*H_DIM + h8;
      const float* tw = &twL[b*260 + tq*32];
      float c[8] = {0.f,0.f,0.f,0.f,0.f,0.f,0.f,0.f};
      #pragma unroll 4
      for (int t = 0; t < 32; ++t) {
        uint2 ev = *(const uint2*)(eob + (long)t*H_DIM);
        float w = tw[t];
        f32x2 d;
        d = fp8pk2f<0>(ev.x); c[0] += w*d.x; c[1] += w*d.y;
        d = fp8pk2f<1>(ev.x); c[2] += w*d.x; c[3] += w*d.y;
        d = fp8pk2f<0>(ev.y); c[4] += w*d.x; c[5] += w*d.y;
        d = fp8pk2f<1>(ev.y); c[6] += w*d.x; c[7] += w*d.y;
      }
      #pragma unroll
      for (int j = 0; j < 8; ++j) scratch[tq*512 + b*256 + h8 + j] = c[j];
    }
    __syncthreads();
    {
      int b = tid >> 8, h = tid & 255;
      float sum = 0.f;
      #pragma unroll
      for (int q = 0; q < 8; ++q) sum += scratch[q*512 + b*256 + h];
      inpb[b*296 + 9 + h] = __float2bfloat16(sum);
      if (tid < 18) { int bb = tid/9, o = tid - bb*9; inpb[bb*296 + o] = __float2bfloat16(decin[bb*12 + o]); }
    }
    __syncthreads();

    // 6. GRU gates + in-register combine
    {
      f32x4 gia[6] = {};
      #pragma unroll
      for (int kc = 0; kc < 9; ++kc) {
        s16x8 a = *(const s16x8*)&inpb[nrow*296 + kc*32 + quad*8];
        #pragma unroll
        for (int u = 0; u < 6; ++u) {
          s16x8 bw = *(const s16x8*)(giptr[u] + kc*32);
          gia[u] = mfma16(a, bw, gia[u]);
        }
      }
      f32x4 gha[6] = {};
      #pragma unroll
      for (int kc = 0; kc < 8; ++kc) {
        s16x8 a = *(const s16x8*)&hbL[nrow*264 + kc*32 + quad*8];
        #pragma unroll
        for (int u = 0; u < 6; ++u) {
          s16x8 bw = *(const s16x8*)(ghptr[u] + kc*32);
          gha[u] = mfma16(a, bw, gha[u]);
        }
      }
      if (quad == 0) {
        #pragma unroll
        for (int c = 0; c < 2; ++c) {
          int j = wv*32 + c*16 + nrow;
          #pragma unroll
          for (int r = 0; r < 2; ++r) {
            float rg = fsig(gia[c][r]   + bihL[j]     + gha[c][r]   + bhhL[j]);
            float zg = fsig(gia[2+c][r] + bihL[256+j] + gha[2+c][r] + bhhL[256+j]);
            float ng = ftanh(gia[4+c][r] + bihL[512+j] + rg*(gha[4+c][r] + bhhL[512+j]));
            float hold = hfL[r*260 + j];
            hfL[r*260 + j] = ng + zg*(hold - ng);
          }
        }
      }
    }
    __syncthreads();

    // 7. pred + feedback
    if (tid < 144) {
      int b = tid / 72, rem = tid - b*72;
      int o = rem >> 3, ch = rem & 7;
      float ps = 0.f;
      #pragma unroll
      for (int k = ch*32; k < ch*32 + 32; ++k)
        ps += hfL[b*260 + k] * WfcL[o*260 + k];
      scratch[tid] = ps;
    }
    __syncthreads();
    if (tid < 18) {
      int b = tid / 9, o = tid - b*9;
      float sum = bfcL[o];
      #pragma unroll
      for (int ch = 0; ch < 8; ++ch) sum += scratch[b*72 + o*8 + ch];
      out[((long)(b0+b)*PRED_LEN + s)*9 + o] = sum;
      decin[b*12 + o] = sum;
    }
    __syncthreads();
  }
}

extern "C" void kernel_launch(void* const* d_in, const int* in_sizes, int n_in,
                              void* d_out, int out_size, void* d_ws, size_t ws_size,
                              hipStream_t stream)
{
  const float* x    = (const float*)d_in[0];
  const float* Wa   = (const float*)d_in[1];
  const float* ba   = (const float*)d_in[2];
  const float* va   = (const float*)d_in[3];
  const float* eWih = (const float*)d_in[4];
  const float* eWhh = (const float*)d_in[5];
  const float* ebih = (const float*)d_in[6];
  const float* ebhh = (const float*)d_in[7];
  const float* dWih = (const float*)d_in[8];
  const float* dWhh = (const float*)d_in[9];
  const float* dbih = (const float*)d_in[10];
  const float* dbhh = (const float*)d_in[11];
  const float* Wt   = (const float*)d_in[12];
  const float* bt   = (const float*)d_in[13];
  const float* vt   = (const float*)d_in[14];
  const float* Wfc  = (const float*)d_in[15];
  const float* bfc  = (const float*)d_in[16];
  float* out = (float*)d_out;

  char* ws = (char*)d_ws;
  size_t off = 0;
  bf16* encWF   = (bf16*)(ws + off); off += (size_t)48*8*64*8*sizeof(bf16);
  bf16* wtEncF  = (bf16*)(ws + off); off += (size_t)16*8*64*8*sizeof(bf16);
  bf16* wtDec   = (bf16*)(ws + off); off += (size_t)256*256*sizeof(bf16);
  bf16* whhD    = (bf16*)(ws + off); off += (size_t)768*256*sizeof(bf16);
  bf16* wihPD   = (bf16*)(ws + off); off += (size_t)768*288*sizeof(bf16);
  float* treprs = (float*)(ws + off); off += (size_t)B_TOT*T_LEN*3*sizeof(float);
  float* h_enc  = (float*)(ws + off); off += (size_t)B_TOT*H_DIM*sizeof(float);
  unsigned char* eo8 = (unsigned char*)(ws + off); off += (size_t)B_TOT*T_LEN*H_DIM;
  unsigned char* ep8 = (unsigned char*)(ws + off); off += (size_t)B_TOT*T_LEN*H_DIM;

  if (ws_size < off) return;

  convert_kernel<<<(768*288 + 255)/256, 256, 0, stream>>>(
      eWhh, Wt, dWhh, dWih, encWF, wtEncF, wtDec, whhD, wihPD);
  agent_attn_kernel<<<B_TOT*T_LEN/256, 256, 0, stream>>>(x, Wa, ba, va, treprs);
  encoder_kernel<<<B_TOT/4, 512, 0, stream>>>(encWF, eWih, ebih, ebhh,
                                              treprs, eo8, h_enc);
  proj_kernel<<<B_TOT*T_LEN/64, 256, 0, stream>>>(eo8, wtEncF, ep8);
  decoder_kernel<<<B_TOT/2, 512, 0, stream>>>(x, wtDec, bt, vt, wihPD, whhD, dbih, dbhh,
                                              Wfc, bfc, eo8, ep8, h_enc, out);
}

// Round 9
// 3485.229 us; speedup vs baseline: 1.2548x; 1.2548x over previous
//
#include <hip/hip_runtime.h>
#include <hip/hip_bf16.h>

typedef __hip_bfloat16 bf16;
typedef __attribute__((ext_vector_type(8))) short s16x8;
typedef __attribute__((ext_vector_type(4))) float f32x4;
typedef __attribute__((ext_vector_type(2))) float f32x2;

#define B_TOT 1024
#define T_LEN 256
#define H_DIM 256
#define PRED_LEN 16

__device__ __forceinline__ float b2f(short u) {
  union { unsigned int i; float f; } c;
  c.i = ((unsigned int)(unsigned short)u) << 16;
  return c.f;
}
__device__ __forceinline__ float fsig(float x) {
  return __builtin_amdgcn_rcpf(1.f + __expf(-x));
}
__device__ __forceinline__ float ftanh(float x) {
  return 1.f - 2.f * __builtin_amdgcn_rcpf(1.f + __expf(2.f * x));
}
__device__ __forceinline__ f32x4 mfma16(s16x8 a, s16x8 b, f32x4 c) {
  return __builtin_amdgcn_mfma_f32_16x16x32_bf16(a, b, c, 0, 0, 0);
}
template <int HI>
__device__ __forceinline__ f32x2 fp8pk2f(unsigned int pk) {
  return __builtin_amdgcn_cvt_pk_f32_fp8(pk, HI);
}
__device__ __forceinline__ unsigned char f2fp8(float v) {
  return (unsigned char)(__builtin_amdgcn_cvt_pk_fp8_f32(v, v, 0, 0) & 0xff);
}
__device__ __forceinline__ uint2 pk8fp8(s16x8 hv) {
  unsigned int lo = 0, hi = 0;
  lo = __builtin_amdgcn_cvt_pk_fp8_f32(b2f(hv[0]), b2f(hv[1]), lo, 0);
  lo = __builtin_amdgcn_cvt_pk_fp8_f32(b2f(hv[2]), b2f(hv[3]), lo, 1);
  hi = __builtin_amdgcn_cvt_pk_fp8_f32(b2f(hv[4]), b2f(hv[5]), hi, 0);
  hi = __builtin_amdgcn_cvt_pk_fp8_f32(b2f(hv[6]), b2f(hv[7]), hi, 1);
  uint2 w; w.x = lo; w.y = hi; return w;
}

// ---------- Kernel 0: pack fp32 weights -> bf16 ws layouts ------------------
// rzW (512x544): [dec_Wih(265) | 0(23) | dec_Whh(256)] for r,z gate rows
// nW  (256x288): [dec_Wih_n(265) | 0]   nhW (256x256): dec_Whh_n
// wtDec (256x256): Wt[:,0:256]; encWF/wtEncF: fragment-linear (as before)
__global__ __launch_bounds__(256) void convert_kernel(
    const float* __restrict__ eWhh, const float* __restrict__ Wt,
    const float* __restrict__ dWhh, const float* __restrict__ dWih,
    bf16* __restrict__ encWF, bf16* __restrict__ wtEncF,
    bf16* __restrict__ wtDec, bf16* __restrict__ rzW,
    bf16* __restrict__ nW, bf16* __restrict__ nhW)
{
  int i = blockIdx.x*256 + threadIdx.x;
  if (i < 24576) {           // encWF fragment slots
    int l = i & 63, kc = (i>>6)&7, tile = i>>9;
    int j = tile*16 + (l&15);
    int k = kc*32 + ((l>>4)&3)*8;
    #pragma unroll
    for (int e = 0; e < 8; ++e)
      encWF[i*8+e] = __float2bfloat16(eWhh[j*256 + k + e]);
  } else if (i < 32768) {    // wtEncF fragment slots
    int s = i - 24576;
    int l = s & 63, kc = (s>>6)&7, tile = s>>9;
    int j = tile*16 + (l&15);
    int k = kc*32 + ((l>>4)&3)*8;
    #pragma unroll
    for (int e = 0; e < 8; ++e)
      wtEncF[s*8+e] = __float2bfloat16(Wt[j*512 + 256 + k + e]);
  }
  if (i < 512*544) {
    int g = i / 544, k = i - g*544;
    float v = (k < 265) ? dWih[g*265 + k]
            : (k < 288) ? 0.f : dWhh[g*256 + (k-288)];
    rzW[i] = __float2bfloat16(v);
  }
  if (i < 256*288) {
    int g = i / 288, k = i - g*288;
    nW[i] = __float2bfloat16((k < 265) ? dWih[(512+g)*265 + k] : 0.f);
  }
  if (i < 256*256) {
    int g = i >> 8, k = i & 255;
    nhW[i] = __float2bfloat16(dWhh[(512+g)*256 + k]);
    wtDec[i] = __float2bfloat16(Wt[g*512 + k]);
  }
}

// ---------- Kernel 1: agent attention (unchanged) --------------------------
__global__ __launch_bounds__(256) void agent_attn_kernel(
    const float* __restrict__ x, const float* __restrict__ Wa,
    const float* __restrict__ ba, const float* __restrict__ va,
    float* __restrict__ treprs)
{
  __shared__ float w0[256], w1[256], w2[256], baL[256], vaL[256];
  int tid = threadIdx.x;
  w0[tid] = Wa[tid*3+0];
  w1[tid] = Wa[tid*3+1];
  w2[tid] = Wa[tid*3+2];
  baL[tid] = ba[tid];
  vaL[tid] = va[tid];
  __syncthreads();
  long idx = (long)blockIdx.x * 256 + tid;
  float xa[9];
  #pragma unroll
  for (int i = 0; i < 9; ++i) xa[i] = x[idx*9 + i];
  float s0 = 0.f, s1 = 0.f, s2 = 0.f;
  for (int h = 0; h < 256; ++h) {
    float a0 = w0[h], a1 = w1[h], a2 = w2[h], bb = baL[h], vv = vaL[h];
    s0 += ftanh(a0*xa[0] + a1*xa[1] + a2*xa[2] + bb) * vv;
    s1 += ftanh(a0*xa[3] + a1*xa[4] + a2*xa[5] + bb) * vv;
    s2 += ftanh(a0*xa[6] + a1*xa[7] + a2*xa[8] + bb) * vv;
  }
  float mx = fmaxf(s0, fmaxf(s1, s2));
  float e0 = __expf(s0-mx), e1 = __expf(s1-mx), e2 = __expf(s2-mx);
  float inv = __builtin_amdgcn_rcpf(e0+e1+e2);
  e0 *= inv; e1 *= inv; e2 *= inv;
  treprs[idx*3+0] = e0*xa[0] + e1*xa[3] + e2*xa[6];
  treprs[idx*3+1] = e0*xa[1] + e1*xa[4] + e2*xa[7];
  treprs[idx*3+2] = e0*xa[2] + e1*xa[5] + e2*xa[8];
}

// ---------- Kernel 2: weight-stationary encoder (unchanged from R8) -------
__global__ __launch_bounds__(512, 2) void encoder_kernel(
    const bf16* __restrict__ encWF, const float* __restrict__ eWih,
    const float* __restrict__ ebih, const float* __restrict__ ebhh,
    const float* __restrict__ treprs, unsigned char* __restrict__ eo8,
    float* __restrict__ h_enc)
{
  __shared__ __align__(16) bf16  hbF[8*64*8];
  __shared__ __align__(16) bf16  hb_lin[4*264];
  __shared__ __align__(16) float hf[4*260];
  __shared__ __align__(16) f32x4 wihAll[768];
  __shared__ float bhhnL[256];
  __shared__ float xtL[2][16];

  const int tid = threadIdx.x;
  const int b0 = blockIdx.x * 4;

  for (int i = tid; i < 768; i += 512) {
    f32x4 w;
    w.x = eWih[i*3+0]; w.y = eWih[i*3+1]; w.z = eWih[i*3+2];
    w.w = (i < 512) ? (ebih[i] + ebhh[i]) : ebih[i];
    wihAll[i] = w;
    if (i >= 512) bhhnL[i-512] = ebhh[i];
  }
  for (int i = tid; i < 4*260; i += 512) hf[i] = 0.f;
  for (int i = tid; i < 8*64*8; i += 512) hbF[i] = __float2bfloat16(0.f);
  for (int i = tid; i < 4*264; i += 512) hb_lin[i] = __float2bfloat16(0.f);
  if (tid < 16) {
    int b = tid >> 2, f = tid & 3;
    xtL[0][tid] = (f < 3) ? treprs[((long)(b0+b)*T_LEN + 0)*3 + f] : 0.f;
  }

  const int lane = tid & 63;
  const int wv   = tid >> 6;
  const int nrow = lane & 15;
  const int quad = lane >> 4;

  s16x8 wf[32];
  #pragma unroll
  for (int u = 0; u < 4; ++u) {
    int tile = (u < 2) ? (2*wv + u) : (16 + 2*wv + (u-2));
    #pragma unroll
    for (int kc = 0; kc < 8; ++kc)
      wf[u*8+kc] = *(const s16x8*)(encWF + (((long)tile*8 + kc)*64 + lane)*8);
  }
  __syncthreads();

  for (int t = 0; t < 256; ++t) {
    s16x8 afr[8];
    #pragma unroll
    for (int kc = 0; kc < 8; ++kc)
      afr[kc] = *(const s16x8*)&hbF[(kc*64 + lane)*8];
    if (t >= 1 && tid < 128) {
      int b = tid >> 5, seg = tid & 31;
      s16x8 hv = *(const s16x8*)&hb_lin[b*264 + seg*8];
      *(uint2*)(eo8 + ((long)(b0+b)*T_LEN + (t-1))*H_DIM + seg*8) = pk8fp8(hv);
    }
    __syncthreads();

    f32x4 acc[6] = {};
    #pragma unroll
    for (int kc = 0; kc < 8; ++kc) {
      #pragma unroll
      for (int u = 0; u < 4; ++u)
        acc[u] = mfma16(afr[kc], wf[u*8+kc], acc[u]);
    }
    #pragma unroll
    for (int half = 0; half < 2; ++half) {
      s16x8 nf[8];
      #pragma unroll
      for (int kc = 0; kc < 8; ++kc)
        nf[kc] = *(const s16x8*)(encWF + (((long)(32 + 2*wv + half)*8 + kc)*64 + lane)*8);
      #pragma unroll
      for (int kc = 0; kc < 8; ++kc)
        acc[4+half] = mfma16(afr[kc], nf[kc], acc[4+half]);
    }

    if (t < 255 && tid < 16) {
      int b = tid >> 2, f = tid & 3;
      xtL[(t+1)&1][tid] = (f < 3) ? treprs[((long)(b0+b)*T_LEN + (t+1))*3 + f] : 0.f;
    }

    {
      float x0 = xtL[t & 1][quad*4+0];
      float x1 = xtL[t & 1][quad*4+1];
      float x2 = xtL[t & 1][quad*4+2];
      #pragma unroll
      for (int c = 0; c < 2; ++c) {
        int j = wv*32 + c*16 + nrow;
        f32x4 wr = wihAll[j];
        f32x4 wz = wihAll[256+j];
        f32x4 wn = wihAll[512+j];
        float rg = fsig(wr.x*x0 + wr.y*x1 + wr.z*x2 + wr.w + acc[c][0]);
        float zg = fsig(wz.x*x0 + wz.y*x1 + wz.z*x2 + wz.w + acc[2+c][0]);
        float ng = ftanh(wn.x*x0 + wn.y*x1 + wn.z*x2 + wn.w
                         + rg*(acc[4+c][0] + bhhnL[j]));
        float hold = hf[quad*260 + j];
        float hnew = ng + zg*(hold - ng);
        hf[quad*260 + j] = hnew;
        bf16 hv = __float2bfloat16(hnew);
        hb_lin[quad*264 + j] = hv;
        hbF[((j>>5)*64 + ((j>>3)&3)*16 + 4*quad)*8 + (j&7)] = hv;
      }
    }
    __syncthreads();
  }

  if (tid < 128) {
    int b = tid >> 5, seg = tid & 31;
    s16x8 hv = *(const s16x8*)&hb_lin[b*264 + seg*8];
    *(uint2*)(eo8 + ((long)(b0+b)*T_LEN + 255)*H_DIM + seg*8) = pk8fp8(hv);
  }
  for (int i = tid; i < 4*256; i += 512) {
    int m = i >> 8, j = i & 255;
    h_enc[(long)(b0+m)*H_DIM + j] = hf[m*260 + j];
  }
}

// ---------- Kernel 3: enc_proj GEMM (unchanged) ----------------------------
__global__ __launch_bounds__(256) void proj_kernel(
    const unsigned char* __restrict__ eo8, const bf16* __restrict__ wtEncF,
    unsigned char* __restrict__ ep8)
{
  __shared__ __align__(16) bf16 Asm[4*8*64*8];
  __shared__ __align__(16) unsigned char Cst[64*256];
  const int tid = threadIdx.x;
  const long R0 = (long)blockIdx.x * 64;
  const int lane = tid & 63, wv = tid >> 6;
  const int nrow = lane & 15, quad = lane >> 4;

  #pragma unroll
  for (int s8 = 0; s8 < 8; ++s8) {
    int s = tid + s8*256;
    int l = s & 63, kc = (s>>6)&7, at = s>>9;
    int m = at*16 + (l&15), k = kc*32 + ((l>>4)&3)*8;
    uint2 v = *(const uint2*)(eo8 + (R0+m)*H_DIM + k);
    s16x8 o; f32x2 d;
    d = fp8pk2f<0>(v.x); o[0] = __bfloat16_as_short(__float2bfloat16(d.x)); o[1] = __bfloat16_as_short(__float2bfloat16(d.y));
    d = fp8pk2f<1>(v.x); o[2] = __bfloat16_as_short(__float2bfloat16(d.x)); o[3] = __bfloat16_as_short(__float2bfloat16(d.y));
    d = fp8pk2f<0>(v.y); o[4] = __bfloat16_as_short(__float2bfloat16(d.x)); o[5] = __bfloat16_as_short(__float2bfloat16(d.y));
    d = fp8pk2f<1>(v.y); o[6] = __bfloat16_as_short(__float2bfloat16(d.x)); o[7] = __bfloat16_as_short(__float2bfloat16(d.y));
    *(s16x8*)&Asm[s*8] = o;
  }
  __syncthreads();

  f32x4 acc[16];
  #pragma unroll
  for (int n = 0; n < 16; ++n) acc[n] = f32x4{0.f,0.f,0.f,0.f};
  #pragma unroll
  for (int kc = 0; kc < 8; ++kc) {
    s16x8 a = *(const s16x8*)&Asm[((wv*8 + kc)*64 + lane)*8];
    #pragma unroll
    for (int nt = 0; nt < 16; ++nt) {
      s16x8 b = *(const s16x8*)(wtEncF + ((nt*8 + kc)*64 + lane)*8);
      acc[nt] = mfma16(a, b, acc[nt]);
    }
  }
  #pragma unroll
  for (int nt = 0; nt < 16; ++nt)
    #pragma unroll
    for (int r = 0; r < 4; ++r)
      Cst[(wv*16 + quad*4 + r)*256 + nt*16 + nrow] = f2fp8(acc[nt][r]);
  __syncthreads();

  {
    int row = tid >> 2, seg = tid & 3;
    #pragma unroll
    for (int p = 0; p < 4; ++p)
      *(uint4*)(ep8 + (R0+row)*H_DIM + seg*64 + p*16) =
          *(const uint4*)&Cst[row*256 + seg*64 + p*16];
  }
}

// ---------- Kernel 4: decoder, B_wg=4, 256 wgs; combined-K GRU -------------
// r/z gates via ONE MFMA chain over K=544 ([inp|h]); n-gate split chains
// share the same A-frags. 8 live accs (32 AGPR) vs 12+ before.
__global__ __launch_bounds__(512) void decoder_kernel(
    const float* __restrict__ x, const bf16* __restrict__ wtDec,
    const float* __restrict__ bt, const float* __restrict__ vt,
    const bf16* __restrict__ rzW, const bf16* __restrict__ nW,
    const bf16* __restrict__ nhW,
    const float* __restrict__ dbih, const float* __restrict__ dbhh,
    const float* __restrict__ Wfc, const float* __restrict__ bfc,
    const unsigned char* __restrict__ eo8, const unsigned char* __restrict__ ep8,
    const float* __restrict__ h_enc, float* __restrict__ out)
{
  __shared__ __align__(16) float hfL[4*260];
  __shared__ __align__(16) bf16  hbL[2][16*264];  // double-buffered h
  __shared__ __align__(16) float qL[4*260];
  __shared__ float twL[4*260];
  __shared__ __align__(16) bf16  inpb[16*296];    // [dec_in(9)|ctx(256)|pad]
  __shared__ __align__(16) float vtL[256];
  __shared__ float btL[256];
  __shared__ float bsumL[512];
  __shared__ float bihnL[256];
  __shared__ float bhhnL[256];
  __shared__ __align__(16) float WfcL[9*260];
  __shared__ float bfcL[9];
  __shared__ float decin[48];
  __shared__ __align__(16) float scratch[4096];

  const int tid = threadIdx.x;
  const int b0 = blockIdx.x * 4;

  for (int i = tid; i < 256; i += 512) {
    vtL[i] = vt[i]; btL[i] = bt[i];
    bihnL[i] = dbih[512+i]; bhhnL[i] = dbhh[512+i];
  }
  for (int i = tid; i < 512; i += 512) bsumL[i] = dbih[i] + dbhh[i];
  for (int i = tid; i < 9*256; i += 512) { int o = i >> 8, k = i & 255; WfcL[o*260+k] = Wfc[i]; }
  if (tid < 9) bfcL[tid] = bfc[tid];
  for (int i = tid; i < 4*260; i += 512) { int m = i/260, j = i - m*260; hfL[i] = (j < 256) ? h_enc[(long)(b0+m)*H_DIM + j] : 0.f; }
  for (int i = tid; i < 16*264; i += 512) {
    int m = i/264, j = i - m*264;
    bf16 hv = (m < 4 && j < 256) ? __float2bfloat16(h_enc[(long)(b0+m)*H_DIM + j])
                                 : __float2bfloat16(0.f);
    hbL[0][i] = hv;
    hbL[1][i] = __float2bfloat16(0.f);
  }
  for (int i = tid; i < 16*296; i += 512) inpb[i] = __float2bfloat16(0.f);
  if (tid < 36) { int b = tid/9, o = tid - b*9; decin[b*12+o] = x[((long)(b0+b)*T_LEN + (T_LEN-1))*9 + o]; }
  __syncthreads();

  const int lane = tid & 63;
  const int wv   = tid >> 6;
  const int nrow = lane & 15;
  const int quad = lane >> 4;

  const bf16* qptr[2];
  #pragma unroll
  for (int u = 0; u < 2; ++u) {
    int g = wv*32 + u*16 + nrow;
    qptr[u] = wtDec + (long)g*H_DIM + quad*8;
  }
  const bf16* rzptr[4];
  #pragma unroll
  for (int u = 0; u < 4; ++u) {
    int g = (u < 2) ? ((2*wv + u)*16 + nrow) : (256 + (2*wv + (u-2))*16 + nrow);
    rzptr[u] = rzW + (long)g*544 + quad*8;
  }
  const bf16* niptr[2];
  const bf16* nhptr[2];
  #pragma unroll
  for (int u = 0; u < 2; ++u) {
    int g = (2*wv + u)*16 + nrow;
    niptr[u] = nW + (long)g*288 + quad*8;
    nhptr[u] = nhW + (long)g*H_DIM + quad*8;
  }

  for (int s = 0; s < PRED_LEN; ++s) {
    const int cur = s & 1, nxt = cur ^ 1;

    // 1. q = h @ Wt_dec^T + bt (A from hbL[cur])
    {
      f32x4 qacc[2] = {};
      #pragma unroll
      for (int kc = 0; kc < 8; ++kc) {
        s16x8 a = *(const s16x8*)&hbL[cur][nrow*264 + kc*32 + quad*8];
        #pragma unroll
        for (int u = 0; u < 2; ++u) {
          s16x8 bw = *(const s16x8*)(qptr[u] + kc*32);
          qacc[u] = mfma16(a, bw, qacc[u]);
        }
      }
      if (quad == 0) {
        #pragma unroll
        for (int u = 0; u < 2; ++u) {
          int g = wv*32 + u*16 + nrow;
          #pragma unroll
          for (int r = 0; r < 4; ++r)
            qL[r*260 + g] = qacc[u][r] + btL[g];
        }
      }
    }
    __syncthreads();

    // 2. scores (4-way split accumulators)
    {
      int bb = tid >> 7, tt = tid & 127;
      #pragma unroll
      for (int p = 0; p < 2; ++p) {
        int t = tt + p*128;
        const uint4* ep4 = (const uint4*)(ep8 + ((long)(b0+bb)*T_LEN + t)*H_DIM);
        const float* qrow = &qL[bb*260];
        float s0 = 0.f, s1 = 0.f, s2 = 0.f, s3 = 0.f;
        #pragma unroll
        for (int kc = 0; kc < 16; ++kc) {
          uint4 pv = ep4[kc];
          float vals[16];
          f32x2 d;
          d = fp8pk2f<0>(pv.x); vals[0]=d.x;  vals[1]=d.y;
          d = fp8pk2f<1>(pv.x); vals[2]=d.x;  vals[3]=d.y;
          d = fp8pk2f<0>(pv.y); vals[4]=d.x;  vals[5]=d.y;
          d = fp8pk2f<1>(pv.y); vals[6]=d.x;  vals[7]=d.y;
          d = fp8pk2f<0>(pv.z); vals[8]=d.x;  vals[9]=d.y;
          d = fp8pk2f<1>(pv.z); vals[10]=d.x; vals[11]=d.y;
          d = fp8pk2f<0>(pv.w); vals[12]=d.x; vals[13]=d.y;
          d = fp8pk2f<1>(pv.w); vals[14]=d.x; vals[15]=d.y;
          #pragma unroll
          for (int j = 0; j < 4; ++j) {
            s0 += ftanh(vals[4*j+0] + qrow[kc*16+4*j+0]) * vtL[kc*16+4*j+0];
            s1 += ftanh(vals[4*j+1] + qrow[kc*16+4*j+1]) * vtL[kc*16+4*j+1];
            s2 += ftanh(vals[4*j+2] + qrow[kc*16+4*j+2]) * vtL[kc*16+4*j+2];
            s3 += ftanh(vals[4*j+3] + qrow[kc*16+4*j+3]) * vtL[kc*16+4*j+3];
          }
        }
        scratch[bb*256 + t] = (s0+s1) + (s2+s3);
      }
    }
    __syncthreads();

    // 3. softmax over t (wave b handles batch row b)
    if (wv < 4) {
      float v4[4];
      float mx = -1e30f;
      #pragma unroll
      for (int i = 0; i < 4; ++i) { v4[i] = scratch[wv*256 + lane + 64*i]; mx = fmaxf(mx, v4[i]); }
      #pragma unroll
      for (int off = 1; off < 64; off <<= 1) mx = fmaxf(mx, __shfl_xor(mx, off));
      float sum = 0.f;
      #pragma unroll
      for (int i = 0; i < 4; ++i) { v4[i] = __expf(v4[i] - mx); sum += v4[i]; }
      #pragma unroll
      for (int off = 1; off < 64; off <<= 1) sum += __shfl_xor(sum, off);
      float inv = __builtin_amdgcn_rcpf(sum);
      #pragma unroll
      for (int i = 0; i < 4; ++i) twL[wv*260 + lane + 64*i] = v4[i] * inv;
    }
    __syncthreads();

    // 4. context partials
    {
      int tq = tid >> 7, b = (tid >> 5) & 3, h8 = (tid & 31) * 8;
      const unsigned char* eob = eo8 + ((long)(b0+b)*T_LEN + tq*64)*H_DIM + h8;
      const float* tw = &twL[b*260 + tq*64];
      float c[8] = {0.f,0.f,0.f,0.f,0.f,0.f,0.f,0.f};
      #pragma unroll 4
      for (int t = 0; t < 64; ++t) {
        uint2 ev = *(const uint2*)(eob + (long)t*H_DIM);
        float w = tw[t];
        f32x2 d;
        d = fp8pk2f<0>(ev.x); c[0] += w*d.x; c[1] += w*d.y;
        d = fp8pk2f<1>(ev.x); c[2] += w*d.x; c[3] += w*d.y;
        d = fp8pk2f<0>(ev.y); c[4] += w*d.x; c[5] += w*d.y;
        d = fp8pk2f<1>(ev.y); c[6] += w*d.x; c[7] += w*d.y;
      }
      #pragma unroll
      for (int j = 0; j < 8; ++j) scratch[tq*1024 + b*256 + h8 + j] = c[j];
    }
    __syncthreads();
    // 5. reduce -> inpb ctx + dec_in
    {
      #pragma unroll
      for (int p = 0; p < 2; ++p) {
        int idx = tid + p*512;
        int b = idx >> 8, h = idx & 255;
        float sum = scratch[b*256 + h] + scratch[1024 + b*256 + h]
                  + scratch[2048 + b*256 + h] + scratch[3072 + b*256 + h];
        inpb[b*296 + 9 + h] = __float2bfloat16(sum);
      }
      if (tid < 36) { int b = tid/9, o = tid - b*9; inpb[b*296 + o] = __float2bfloat16(decin[b*12 + o]); }
    }
    __syncthreads();

    // 6. GRU: combined-K r/z + split n; combine -> hfL, hbL[nxt]
    {
      f32x4 arz[4] = {};
      f32x4 ani[2] = {};
      f32x4 anh[2] = {};
      #pragma unroll
      for (int kc = 0; kc < 17; ++kc) {
        s16x8 a = (kc < 9)
          ? *(const s16x8*)&inpb[nrow*296 + kc*32 + quad*8]
          : *(const s16x8*)&hbL[cur][nrow*264 + (kc-9)*32 + quad*8];
        #pragma unroll
        for (int u = 0; u < 4; ++u)
          arz[u] = mfma16(a, *(const s16x8*)(rzptr[u] + kc*32), arz[u]);
        if (kc < 9) {
          ani[0] = mfma16(a, *(const s16x8*)(niptr[0] + kc*32), ani[0]);
          ani[1] = mfma16(a, *(const s16x8*)(niptr[1] + kc*32), ani[1]);
        } else {
          anh[0] = mfma16(a, *(const s16x8*)(nhptr[0] + (kc-9)*32), anh[0]);
          anh[1] = mfma16(a, *(const s16x8*)(nhptr[1] + (kc-9)*32), anh[1]);
        }
      }
      if (quad == 0) {
        #pragma unroll
        for (int c = 0; c < 2; ++c) {
          int j = wv*32 + c*16 + nrow;
          #pragma unroll
          for (int r = 0; r < 4; ++r) {
            float rg = fsig(arz[c][r]   + bsumL[j]);
            float zg = fsig(arz[2+c][r] + bsumL[256+j]);
            float ng = ftanh(ani[c][r] + bihnL[j] + rg*(anh[c][r] + bhhnL[j]));
            float hold = hfL[r*260 + j];
            float hnew = ng + zg*(hold - ng);
            hfL[r*260 + j] = hnew;
            hbL[nxt][r*264 + j] = __float2bfloat16(hnew);
          }
        }
      }
    }
    __syncthreads();

    // 7. pred = h_new @ Wfc^T + bfc
    if (tid < 288) {
      int b = tid / 72, rem = tid - b*72;
      int o = rem >> 3, ch = rem & 7;
      float ps = 0.f;
      #pragma unroll
      for (int k = ch*32; k < ch*32 + 32; ++k)
        ps += hfL[b*260 + k] * WfcL[o*260 + k];
      scratch[tid] = ps;
    }
    __syncthreads();
    if (tid < 36) {
      int b = tid / 9, o = tid - b*9;
      float sum = bfcL[o];
      #pragma unroll
      for (int ch = 0; ch < 8; ++ch) sum += scratch[b*72 + o*8 + ch];
      out[((long)(b0+b)*PRED_LEN + s)*9 + o] = sum;
      decin[b*12 + o] = sum;
    }
    __syncthreads();
  }
}

extern "C" void kernel_launch(void* const* d_in, const int* in_sizes, int n_in,
                              void* d_out, int out_size, void* d_ws, size_t ws_size,
                              hipStream_t stream)
{
  const float* x    = (const float*)d_in[0];
  const float* Wa   = (const float*)d_in[1];
  const float* ba   = (const float*)d_in[2];
  const float* va   = (const float*)d_in[3];
  const float* eWih = (const float*)d_in[4];
  const float* eWhh = (const float*)d_in[5];
  const float* ebih = (const float*)d_in[6];
  const float* ebhh = (const float*)d_in[7];
  const float* dWih = (const float*)d_in[8];
  const float* dWhh = (const float*)d_in[9];
  const float* dbih = (const float*)d_in[10];
  const float* dbhh = (const float*)d_in[11];
  const float* Wt   = (const float*)d_in[12];
  const float* bt   = (const float*)d_in[13];
  const float* vt   = (const float*)d_in[14];
  const float* Wfc  = (const float*)d_in[15];
  const float* bfc  = (const float*)d_in[16];
  float* out = (float*)d_out;

  char* ws = (char*)d_ws;
  size_t off = 0;
  bf16* encWF   = (bf16*)(ws + off); off += (size_t)48*8*64*8*sizeof(bf16);
  bf16* wtEncF  = (bf16*)(ws + off); off += (size_t)16*8*64*8*sizeof(bf16);
  bf16* wtDec   = (bf16*)(ws + off); off += (size_t)256*256*sizeof(bf16);
  bf16* rzW     = (bf16*)(ws + off); off += (size_t)512*544*sizeof(bf16);
  bf16* nW      = (bf16*)(ws + off); off += (size_t)256*288*sizeof(bf16);
  bf16* nhW     = (bf16*)(ws + off); off += (size_t)256*256*sizeof(bf16);
  float* treprs = (float*)(ws + off); off += (size_t)B_TOT*T_LEN*3*sizeof(float);
  float* h_enc  = (float*)(ws + off); off += (size_t)B_TOT*H_DIM*sizeof(float);
  unsigned char* eo8 = (unsigned char*)(ws + off); off += (size_t)B_TOT*T_LEN*H_DIM;
  unsigned char* ep8 = (unsigned char*)(ws + off); off += (size_t)B_TOT*T_LEN*H_DIM;

  if (ws_size < off) return;

  convert_kernel<<<(512*544 + 255)/256, 256, 0, stream>>>(
      eWhh, Wt, dWhh, dWih, encWF, wtEncF, wtDec, rzW, nW, nhW);
  agent_attn_kernel<<<B_TOT*T_LEN/256, 256, 0, stream>>>(x, Wa, ba, va, treprs);
  encoder_kernel<<<B_TOT/4, 512, 0, stream>>>(encWF, eWih, ebih, ebhh,
                                              treprs, eo8, h_enc);
  proj_kernel<<<B_TOT*T_LEN/64, 256, 0, stream>>>(eo8, wtEncF, ep8);
  decoder_kernel<<<B_TOT/4, 512, 0, stream>>>(x, wtDec, bt, vt, rzW, nW, nhW,
                                              dbih, dbhh, Wfc, bfc, eo8, ep8,
                                              h_enc, out);
}

// Round 10
// 2634.162 us; speedup vs baseline: 1.6602x; 1.3231x over previous
//
#include <hip/hip_runtime.h>
#include <hip/hip_bf16.h>

typedef __hip_bfloat16 bf16;
typedef __attribute__((ext_vector_type(8))) short s16x8;
typedef __attribute__((ext_vector_type(4))) float f32x4;
typedef __attribute__((ext_vector_type(2))) float f32x2;

#define B_TOT 1024
#define T_LEN 256
#define H_DIM 256
#define PRED_LEN 16

__device__ __forceinline__ float b2f(short u) {
  union { unsigned int i; float f; } c;
  c.i = ((unsigned int)(unsigned short)u) << 16;
  return c.f;
}
__device__ __forceinline__ float fsig(float x) {
  return __builtin_amdgcn_rcpf(1.f + __expf(-x));
}
__device__ __forceinline__ float ftanh(float x) {
  return 1.f - 2.f * __builtin_amdgcn_rcpf(1.f + __expf(2.f * x));
}
__device__ __forceinline__ f32x4 mfma16(s16x8 a, s16x8 b, f32x4 c) {
  return __builtin_amdgcn_mfma_f32_16x16x32_bf16(a, b, c, 0, 0, 0);
}
template <int HI>
__device__ __forceinline__ f32x2 fp8pk2f(unsigned int pk) {
  return __builtin_amdgcn_cvt_pk_f32_fp8(pk, HI);
}
__device__ __forceinline__ unsigned char f2fp8(float v) {
  return (unsigned char)(__builtin_amdgcn_cvt_pk_fp8_f32(v, v, 0, 0) & 0xff);
}
__device__ __forceinline__ uint2 pk8fp8(s16x8 hv) {
  unsigned int lo = 0, hi = 0;
  lo = __builtin_amdgcn_cvt_pk_fp8_f32(b2f(hv[0]), b2f(hv[1]), lo, 0);
  lo = __builtin_amdgcn_cvt_pk_fp8_f32(b2f(hv[2]), b2f(hv[3]), lo, 1);
  hi = __builtin_amdgcn_cvt_pk_fp8_f32(b2f(hv[4]), b2f(hv[5]), hi, 0);
  hi = __builtin_amdgcn_cvt_pk_fp8_f32(b2f(hv[6]), b2f(hv[7]), hi, 1);
  uint2 w; w.x = lo; w.y = hi; return w;
}

// ---------- Kernel 0: pack fp32 weights -> bf16 ws layouts (R6 layouts) ----
__global__ __launch_bounds__(256) void convert_kernel(
    const float* __restrict__ eWhh, const float* __restrict__ Wt,
    const float* __restrict__ dWhh, const float* __restrict__ dWih,
    bf16* __restrict__ encWF, bf16* __restrict__ wtEncF,
    bf16* __restrict__ wtDec, bf16* __restrict__ whhD, bf16* __restrict__ wihPD)
{
  int i = blockIdx.x*256 + threadIdx.x;
  if (i < 24576) {           // encWF fragment slots
    int l = i & 63, kc = (i>>6)&7, tile = i>>9;
    int j = tile*16 + (l&15);
    int k = kc*32 + ((l>>4)&3)*8;
    #pragma unroll
    for (int e = 0; e < 8; ++e)
      encWF[i*8+e] = __float2bfloat16(eWhh[j*256 + k + e]);
  } else if (i < 32768) {    // wtEncF fragment slots
    int s = i - 24576;
    int l = s & 63, kc = (s>>6)&7, tile = s>>9;
    int j = tile*16 + (l&15);
    int k = kc*32 + ((l>>4)&3)*8;
    #pragma unroll
    for (int e = 0; e < 8; ++e)
      wtEncF[s*8+e] = __float2bfloat16(Wt[j*512 + 256 + k + e]);
  }
  if (i < 768*288) {
    int g = i / 288, k = i - g*288;
    wihPD[i] = __float2bfloat16((k < 265) ? dWih[g*265 + k] : 0.f);
  }
  if (i < 256*256) {
    int g = i >> 8, k = i & 255;
    wtDec[i] = __float2bfloat16(Wt[g*512 + k]);
  }
  if (i < 768*256) whhD[i] = __float2bfloat16(dWhh[i]);
}

// ---------- Kernel 1: agent attention (unchanged) --------------------------
__global__ __launch_bounds__(256) void agent_attn_kernel(
    const float* __restrict__ x, const float* __restrict__ Wa,
    const float* __restrict__ ba, const float* __restrict__ va,
    float* __restrict__ treprs)
{
  __shared__ float w0[256], w1[256], w2[256], baL[256], vaL[256];
  int tid = threadIdx.x;
  w0[tid] = Wa[tid*3+0];
  w1[tid] = Wa[tid*3+1];
  w2[tid] = Wa[tid*3+2];
  baL[tid] = ba[tid];
  vaL[tid] = va[tid];
  __syncthreads();
  long idx = (long)blockIdx.x * 256 + tid;
  float xa[9];
  #pragma unroll
  for (int i = 0; i < 9; ++i) xa[i] = x[idx*9 + i];
  float s0 = 0.f, s1 = 0.f, s2 = 0.f;
  for (int h = 0; h < 256; ++h) {
    float a0 = w0[h], a1 = w1[h], a2 = w2[h], bb = baL[h], vv = vaL[h];
    s0 += ftanh(a0*xa[0] + a1*xa[1] + a2*xa[2] + bb) * vv;
    s1 += ftanh(a0*xa[3] + a1*xa[4] + a2*xa[5] + bb) * vv;
    s2 += ftanh(a0*xa[6] + a1*xa[7] + a2*xa[8] + bb) * vv;
  }
  float mx = fmaxf(s0, fmaxf(s1, s2));
  float e0 = __expf(s0-mx), e1 = __expf(s1-mx), e2 = __expf(s2-mx);
  float inv = __builtin_amdgcn_rcpf(e0+e1+e2);
  e0 *= inv; e1 *= inv; e2 *= inv;
  treprs[idx*3+0] = e0*xa[0] + e1*xa[3] + e2*xa[6];
  treprs[idx*3+1] = e0*xa[1] + e1*xa[4] + e2*xa[7];
  treprs[idx*3+2] = e0*xa[2] + e1*xa[5] + e2*xa[8];
}

// ---------- Kernel 2: weight-stationary encoder (unchanged) ----------------
__global__ __launch_bounds__(512, 2) void encoder_kernel(
    const bf16* __restrict__ encWF, const float* __restrict__ eWih,
    const float* __restrict__ ebih, const float* __restrict__ ebhh,
    const float* __restrict__ treprs, unsigned char* __restrict__ eo8,
    float* __restrict__ h_enc)
{
  __shared__ __align__(16) bf16  hbF[8*64*8];
  __shared__ __align__(16) bf16  hb_lin[4*264];
  __shared__ __align__(16) float hf[4*260];
  __shared__ __align__(16) f32x4 wihAll[768];
  __shared__ float bhhnL[256];
  __shared__ float xtL[2][16];

  const int tid = threadIdx.x;
  const int b0 = blockIdx.x * 4;

  for (int i = tid; i < 768; i += 512) {
    f32x4 w;
    w.x = eWih[i*3+0]; w.y = eWih[i*3+1]; w.z = eWih[i*3+2];
    w.w = (i < 512) ? (ebih[i] + ebhh[i]) : ebih[i];
    wihAll[i] = w;
    if (i >= 512) bhhnL[i-512] = ebhh[i];
  }
  for (int i = tid; i < 4*260; i += 512) hf[i] = 0.f;
  for (int i = tid; i < 8*64*8; i += 512) hbF[i] = __float2bfloat16(0.f);
  for (int i = tid; i < 4*264; i += 512) hb_lin[i] = __float2bfloat16(0.f);
  if (tid < 16) {
    int b = tid >> 2, f = tid & 3;
    xtL[0][tid] = (f < 3) ? treprs[((long)(b0+b)*T_LEN + 0)*3 + f] : 0.f;
  }

  const int lane = tid & 63;
  const int wv   = tid >> 6;
  const int nrow = lane & 15;
  const int quad = lane >> 4;

  s16x8 wf[32];
  #pragma unroll
  for (int u = 0; u < 4; ++u) {
    int tile = (u < 2) ? (2*wv + u) : (16 + 2*wv + (u-2));
    #pragma unroll
    for (int kc = 0; kc < 8; ++kc)
      wf[u*8+kc] = *(const s16x8*)(encWF + (((long)tile*8 + kc)*64 + lane)*8);
  }
  __syncthreads();

  for (int t = 0; t < 256; ++t) {
    s16x8 afr[8];
    #pragma unroll
    for (int kc = 0; kc < 8; ++kc)
      afr[kc] = *(const s16x8*)&hbF[(kc*64 + lane)*8];
    if (t >= 1 && tid < 128) {
      int b = tid >> 5, seg = tid & 31;
      s16x8 hv = *(const s16x8*)&hb_lin[b*264 + seg*8];
      *(uint2*)(eo8 + ((long)(b0+b)*T_LEN + (t-1))*H_DIM + seg*8) = pk8fp8(hv);
    }
    __syncthreads();

    f32x4 acc[6] = {};
    #pragma unroll
    for (int kc = 0; kc < 8; ++kc) {
      #pragma unroll
      for (int u = 0; u < 4; ++u)
        acc[u] = mfma16(afr[kc], wf[u*8+kc], acc[u]);
    }
    #pragma unroll
    for (int half = 0; half < 2; ++half) {
      s16x8 nf[8];
      #pragma unroll
      for (int kc = 0; kc < 8; ++kc)
        nf[kc] = *(const s16x8*)(encWF + (((long)(32 + 2*wv + half)*8 + kc)*64 + lane)*8);
      #pragma unroll
      for (int kc = 0; kc < 8; ++kc)
        acc[4+half] = mfma16(afr[kc], nf[kc], acc[4+half]);
    }

    if (t < 255 && tid < 16) {
      int b = tid >> 2, f = tid & 3;
      xtL[(t+1)&1][tid] = (f < 3) ? treprs[((long)(b0+b)*T_LEN + (t+1))*3 + f] : 0.f;
    }

    {
      float x0 = xtL[t & 1][quad*4+0];
      float x1 = xtL[t & 1][quad*4+1];
      float x2 = xtL[t & 1][quad*4+2];
      #pragma unroll
      for (int c = 0; c < 2; ++c) {
        int j = wv*32 + c*16 + nrow;
        f32x4 wr = wihAll[j];
        f32x4 wz = wihAll[256+j];
        f32x4 wn = wihAll[512+j];
        float rg = fsig(wr.x*x0 + wr.y*x1 + wr.z*x2 + wr.w + acc[c][0]);
        float zg = fsig(wz.x*x0 + wz.y*x1 + wz.z*x2 + wz.w + acc[2+c][0]);
        float ng = ftanh(wn.x*x0 + wn.y*x1 + wn.z*x2 + wn.w
                         + rg*(acc[4+c][0] + bhhnL[j]));
        float hold = hf[quad*260 + j];
        float hnew = ng + zg*(hold - ng);
        hf[quad*260 + j] = hnew;
        bf16 hv = __float2bfloat16(hnew);
        hb_lin[quad*264 + j] = hv;
        hbF[((j>>5)*64 + ((j>>3)&3)*16 + 4*quad)*8 + (j&7)] = hv;
      }
    }
    __syncthreads();
  }

  if (tid < 128) {
    int b = tid >> 5, seg = tid & 31;
    s16x8 hv = *(const s16x8*)&hb_lin[b*264 + seg*8];
    *(uint2*)(eo8 + ((long)(b0+b)*T_LEN + 255)*H_DIM + seg*8) = pk8fp8(hv);
  }
  for (int i = tid; i < 4*256; i += 512) {
    int m = i >> 8, j = i & 255;
    h_enc[(long)(b0+m)*H_DIM + j] = hf[m*260 + j];
  }
}

// ---------- Kernel 3: enc_proj GEMM (unchanged) ----------------------------
__global__ __launch_bounds__(256) void proj_kernel(
    const unsigned char* __restrict__ eo8, const bf16* __restrict__ wtEncF,
    unsigned char* __restrict__ ep8)
{
  __shared__ __align__(16) bf16 Asm[4*8*64*8];
  __shared__ __align__(16) unsigned char Cst[64*256];
  const int tid = threadIdx.x;
  const long R0 = (long)blockIdx.x * 64;
  const int lane = tid & 63, wv = tid >> 6;
  const int nrow = lane & 15, quad = lane >> 4;

  #pragma unroll
  for (int s8 = 0; s8 < 8; ++s8) {
    int s = tid + s8*256;
    int l = s & 63, kc = (s>>6)&7, at = s>>9;
    int m = at*16 + (l&15), k = kc*32 + ((l>>4)&3)*8;
    uint2 v = *(const uint2*)(eo8 + (R0+m)*H_DIM + k);
    s16x8 o; f32x2 d;
    d = fp8pk2f<0>(v.x); o[0] = __bfloat16_as_short(__float2bfloat16(d.x)); o[1] = __bfloat16_as_short(__float2bfloat16(d.y));
    d = fp8pk2f<1>(v.x); o[2] = __bfloat16_as_short(__float2bfloat16(d.x)); o[3] = __bfloat16_as_short(__float2bfloat16(d.y));
    d = fp8pk2f<0>(v.y); o[4] = __bfloat16_as_short(__float2bfloat16(d.x)); o[5] = __bfloat16_as_short(__float2bfloat16(d.y));
    d = fp8pk2f<1>(v.y); o[6] = __bfloat16_as_short(__float2bfloat16(d.x)); o[7] = __bfloat16_as_short(__float2bfloat16(d.y));
    *(s16x8*)&Asm[s*8] = o;
  }
  __syncthreads();

  f32x4 acc[16];
  #pragma unroll
  for (int n = 0; n < 16; ++n) acc[n] = f32x4{0.f,0.f,0.f,0.f};
  #pragma unroll
  for (int kc = 0; kc < 8; ++kc) {
    s16x8 a = *(const s16x8*)&Asm[((wv*8 + kc)*64 + lane)*8];
    #pragma unroll
    for (int nt = 0; nt < 16; ++nt) {
      s16x8 b = *(const s16x8*)(wtEncF + ((nt*8 + kc)*64 + lane)*8);
      acc[nt] = mfma16(a, b, acc[nt]);
    }
  }
  #pragma unroll
  for (int nt = 0; nt < 16; ++nt)
    #pragma unroll
    for (int r = 0; r < 4; ++r)
      Cst[(wv*16 + quad*4 + r)*256 + nt*16 + nrow] = f2fp8(acc[nt][r]);
  __syncthreads();

  {
    int row = tid >> 2, seg = tid & 3;
    #pragma unroll
    for (int p = 0; p < 4; ++p)
      *(uint4*)(ep8 + (R0+row)*H_DIM + seg*64 + p*16) =
          *(const uint4*)&Cst[row*256 + seg*64 + p*16];
  }
}

// ---------- Kernel 4: decoder, 1024 thr, B_wg=8, 128 wgs -------------------
// 16 waves; wave w owns ONE gate-column tile jr = w*16+nrow. Phase 1: q+gh
// (4 accs, A=h); gh accs live across attention; phase 3: gi (3 accs, A=inp)
// + combine. Score loop de-unrolled, immediate consumption, 2 accumulators.
__global__ __launch_bounds__(1024) void decoder_kernel(
    const float* __restrict__ x, const bf16* __restrict__ wtDec,
    const float* __restrict__ bt, const float* __restrict__ vt,
    const bf16* __restrict__ wihPD, const bf16* __restrict__ whhD,
    const float* __restrict__ dbih, const float* __restrict__ dbhh,
    const float* __restrict__ Wfc, const float* __restrict__ bfc,
    const unsigned char* __restrict__ eo8, const unsigned char* __restrict__ ep8,
    const float* __restrict__ h_enc, float* __restrict__ out)
{
  __shared__ __align__(16) float hfL[8*260];
  __shared__ __align__(16) bf16  hbL[16*264];   // rows 8..15 stay zero
  __shared__ __align__(16) float qL[8*260];
  __shared__ float twL[8*260];
  __shared__ __align__(16) bf16  inpb[16*296];  // rows 8..15 stay zero
  __shared__ __align__(16) float vtL[256];
  __shared__ float btL[256];
  __shared__ float bsumL[512];
  __shared__ float bihnL[256];
  __shared__ float bhhnL[256];
  __shared__ __align__(16) float WfcL[9*260];
  __shared__ float bfcL[9];
  __shared__ float decin[96];
  __shared__ __align__(16) float scratch[4096];

  const int tid = threadIdx.x;
  const int b0 = blockIdx.x * 8;

  for (int i = tid; i < 256; i += 1024) {
    vtL[i] = vt[i]; btL[i] = bt[i];
    bihnL[i] = dbih[512+i]; bhhnL[i] = dbhh[512+i];
  }
  if (tid < 512) bsumL[tid] = dbih[tid] + dbhh[tid];
  for (int i = tid; i < 9*256; i += 1024) { int o = i >> 8, k = i & 255; WfcL[o*260+k] = Wfc[i]; }
  if (tid < 9) bfcL[tid] = bfc[tid];
  for (int i = tid; i < 8*260; i += 1024) { int m = i/260, j = i - m*260; hfL[i] = (j < 256) ? h_enc[(long)(b0+m)*H_DIM + j] : 0.f; }
  for (int i = tid; i < 16*264; i += 1024) {
    int m = i/264, j = i - m*264;
    hbL[i] = (m < 8 && j < 256) ? __float2bfloat16(h_enc[(long)(b0+m)*H_DIM + j])
                                : __float2bfloat16(0.f);
  }
  for (int i = tid; i < 16*296; i += 1024) inpb[i] = __float2bfloat16(0.f);
  if (tid < 72) { int b = tid/9, o = tid - b*9; decin[b*12+o] = x[((long)(b0+b)*T_LEN + (T_LEN-1))*9 + o]; }
  __syncthreads();

  const int lane = tid & 63;
  const int wv   = tid >> 6;          // 0..15
  const int nrow = lane & 15;
  const int quad = lane >> 4;
  const int jr   = wv*16 + nrow;      // this wave's gate/q column

  for (int s = 0; s < PRED_LEN; ++s) {
    // ---- phase 1: q + gh MFMAs (A = hbL) ----
    f32x4 qa = {}, ghr = {}, ghz = {}, ghn = {};
    #pragma unroll
    for (int kc = 0; kc < 8; ++kc) {
      s16x8 a = *(const s16x8*)&hbL[nrow*264 + kc*32 + quad*8];
      qa  = mfma16(a, *(const s16x8*)(wtDec + (long)jr*256 + kc*32 + quad*8), qa);
      ghr = mfma16(a, *(const s16x8*)(whhD + (long)jr*256 + kc*32 + quad*8), ghr);
      ghz = mfma16(a, *(const s16x8*)(whhD + (long)(256+jr)*256 + kc*32 + quad*8), ghz);
      ghn = mfma16(a, *(const s16x8*)(whhD + (long)(512+jr)*256 + kc*32 + quad*8), ghn);
    }
    if (quad < 2) {
      #pragma unroll
      for (int r = 0; r < 4; ++r)
        qL[(quad*4+r)*260 + jr] = qa[r] + btL[jr];
    }
    __syncthreads();

    // ---- phase 2: scores ----
    {
      int bb = tid >> 7, tt = tid & 127;
      const float* qrow = &qL[bb*260];
      #pragma unroll
      for (int p = 0; p < 2; ++p) {
        int t = tt + p*128;
        const uint4* ep4 = (const uint4*)(ep8 + ((long)(b0+bb)*T_LEN + t)*H_DIM);
        float s0 = 0.f, s1 = 0.f;
        #pragma unroll 2
        for (int kc = 0; kc < 16; ++kc) {
          uint4 pv = ep4[kc];
          int k = kc*16;
          f32x2 d;
          d = fp8pk2f<0>(pv.x); s0 += ftanh(d.x + qrow[k+0])*vtL[k+0];  s1 += ftanh(d.y + qrow[k+1])*vtL[k+1];
          d = fp8pk2f<1>(pv.x); s0 += ftanh(d.x + qrow[k+2])*vtL[k+2];  s1 += ftanh(d.y + qrow[k+3])*vtL[k+3];
          d = fp8pk2f<0>(pv.y); s0 += ftanh(d.x + qrow[k+4])*vtL[k+4];  s1 += ftanh(d.y + qrow[k+5])*vtL[k+5];
          d = fp8pk2f<1>(pv.y); s0 += ftanh(d.x + qrow[k+6])*vtL[k+6];  s1 += ftanh(d.y + qrow[k+7])*vtL[k+7];
          d = fp8pk2f<0>(pv.z); s0 += ftanh(d.x + qrow[k+8])*vtL[k+8];  s1 += ftanh(d.y + qrow[k+9])*vtL[k+9];
          d = fp8pk2f<1>(pv.z); s0 += ftanh(d.x + qrow[k+10])*vtL[k+10]; s1 += ftanh(d.y + qrow[k+11])*vtL[k+11];
          d = fp8pk2f<0>(pv.w); s0 += ftanh(d.x + qrow[k+12])*vtL[k+12]; s1 += ftanh(d.y + qrow[k+13])*vtL[k+13];
          d = fp8pk2f<1>(pv.w); s0 += ftanh(d.x + qrow[k+14])*vtL[k+14]; s1 += ftanh(d.y + qrow[k+15])*vtL[k+15];
        }
        scratch[bb*256 + t] = s0 + s1;
      }
    }
    __syncthreads();

    // ---- phase 2b: softmax (wave b handles batch row b) ----
    if (wv < 8) {
      float v4[4];
      float mx = -1e30f;
      #pragma unroll
      for (int i = 0; i < 4; ++i) { v4[i] = scratch[wv*256 + lane + 64*i]; mx = fmaxf(mx, v4[i]); }
      #pragma unroll
      for (int off = 1; off < 64; off <<= 1) mx = fmaxf(mx, __shfl_xor(mx, off));
      float sum = 0.f;
      #pragma unroll
      for (int i = 0; i < 4; ++i) { v4[i] = __expf(v4[i] - mx); sum += v4[i]; }
      #pragma unroll
      for (int off = 1; off < 64; off <<= 1) sum += __shfl_xor(sum, off);
      float inv = __builtin_amdgcn_rcpf(sum);
      #pragma unroll
      for (int i = 0; i < 4; ++i) twL[wv*260 + lane + 64*i] = v4[i] * inv;
    }
    __syncthreads();

    // ---- phase 2c: context partials (thread: tq of 2, b of 8, 4 h-cols) ----
    {
      int tq = tid >> 9, rem = tid & 511;
      int b = rem >> 6, hc = (rem & 63) * 4;
      const unsigned char* eob = eo8 + ((long)(b0+b)*T_LEN + tq*128)*H_DIM + hc;
      const float* tw = &twL[b*260 + tq*128];
      float c0 = 0.f, c1 = 0.f, c2 = 0.f, c3 = 0.f;
      #pragma unroll 4
      for (int t = 0; t < 128; ++t) {
        unsigned int ev = *(const unsigned int*)(eob + (long)t*H_DIM);
        float w = tw[t];
        f32x2 d0 = fp8pk2f<0>(ev);
        f32x2 d1 = fp8pk2f<1>(ev);
        c0 += w*d0.x; c1 += w*d0.y; c2 += w*d1.x; c3 += w*d1.y;
      }
      scratch[tq*2048 + b*256 + hc + 0] = c0;
      scratch[tq*2048 + b*256 + hc + 1] = c1;
      scratch[tq*2048 + b*256 + hc + 2] = c2;
      scratch[tq*2048 + b*256 + hc + 3] = c3;
    }
    __syncthreads();
    // ---- phase 2d: reduce -> inpb ----
    {
      #pragma unroll
      for (int p = 0; p < 2; ++p) {
        int idx = tid + p*1024;
        int b = idx >> 8, h = idx & 255;
        inpb[b*296 + 9 + h] = __float2bfloat16(scratch[idx] + scratch[2048 + idx]);
      }
      if (tid < 72) { int b = tid/9, o = tid - b*9; inpb[b*296 + o] = __float2bfloat16(decin[b*12 + o]); }
    }
    __syncthreads();

    // ---- phase 3: gi MFMAs (A = inpb) + combine ----
    {
      f32x4 gir = {}, giz = {}, gin = {};
      #pragma unroll
      for (int kc = 0; kc < 9; ++kc) {
        s16x8 a = *(const s16x8*)&inpb[nrow*296 + kc*32 + quad*8];
        gir = mfma16(a, *(const s16x8*)(wihPD + (long)jr*288 + kc*32 + quad*8), gir);
        giz = mfma16(a, *(const s16x8*)(wihPD + (long)(256+jr)*288 + kc*32 + quad*8), giz);
        gin = mfma16(a, *(const s16x8*)(wihPD + (long)(512+jr)*288 + kc*32 + quad*8), gin);
      }
      if (quad < 2) {
        #pragma unroll
        for (int r = 0; r < 4; ++r) {
          int m = quad*4 + r;
          float rg = fsig(gir[r] + ghr[r] + bsumL[jr]);
          float zg = fsig(giz[r] + ghz[r] + bsumL[256+jr]);
          float ng = ftanh(gin[r] + bihnL[jr] + rg*(ghn[r] + bhhnL[jr]));
          float hold = hfL[m*260 + jr];
          float hnew = ng + zg*(hold - ng);
          hfL[m*260 + jr] = hnew;
          hbL[m*264 + jr] = __float2bfloat16(hnew);
        }
      }
    }
    __syncthreads();

    // ---- phase 4: pred = h_new @ Wfc^T + bfc ----
    if (tid < 576) {
      int b = tid / 72, rem = tid - b*72;
      int o = rem >> 3, ch = rem & 7;
      float ps = 0.f;
      #pragma unroll
      for (int k = ch*32; k < ch*32 + 32; ++k)
        ps += hfL[b*260 + k] * WfcL[o*260 + k];
      scratch[tid] = ps;
    }
    __syncthreads();
    if (tid < 72) {
      int b = tid / 9, o = tid - b*9;
      float sum = bfcL[o];
      #pragma unroll
      for (int ch = 0; ch < 8; ++ch) sum += scratch[b*72 + o*8 + ch];
      out[((long)(b0+b)*PRED_LEN + s)*9 + o] = sum;
      decin[b*12 + o] = sum;
    }
    __syncthreads();
  }
}

extern "C" void kernel_launch(void* const* d_in, const int* in_sizes, int n_in,
                              void* d_out, int out_size, void* d_ws, size_t ws_size,
                              hipStream_t stream)
{
  const float* x    = (const float*)d_in[0];
  const float* Wa   = (const float*)d_in[1];
  const float* ba   = (const float*)d_in[2];
  const float* va   = (const float*)d_in[3];
  const float* eWih = (const float*)d_in[4];
  const float* eWhh = (const float*)d_in[5];
  const float* ebih = (const float*)d_in[6];
  const float* ebhh = (const float*)d_in[7];
  const float* dWih = (const float*)d_in[8];
  const float* dWhh = (const float*)d_in[9];
  const float* dbih = (const float*)d_in[10];
  const float* dbhh = (const float*)d_in[11];
  const float* Wt   = (const float*)d_in[12];
  const float* bt   = (const float*)d_in[13];
  const float* vt   = (const float*)d_in[14];
  const float* Wfc  = (const float*)d_in[15];
  const float* bfc  = (const float*)d_in[16];
  float* out = (float*)d_out;

  char* ws = (char*)d_ws;
  size_t off = 0;
  bf16* encWF   = (bf16*)(ws + off); off += (size_t)48*8*64*8*sizeof(bf16);
  bf16* wtEncF  = (bf16*)(ws + off); off += (size_t)16*8*64*8*sizeof(bf16);
  bf16* wtDec   = (bf16*)(ws + off); off += (size_t)256*256*sizeof(bf16);
  bf16* whhD    = (bf16*)(ws + off); off += (size_t)768*256*sizeof(bf16);
  bf16* wihPD   = (bf16*)(ws + off); off += (size_t)768*288*sizeof(bf16);
  float* treprs = (float*)(ws + off); off += (size_t)B_TOT*T_LEN*3*sizeof(float);
  float* h_enc  = (float*)(ws + off); off += (size_t)B_TOT*H_DIM*sizeof(float);
  unsigned char* eo8 = (unsigned char*)(ws + off); off += (size_t)B_TOT*T_LEN*H_DIM;
  unsigned char* ep8 = (unsigned char*)(ws + off); off += (size_t)B_TOT*T_LEN*H_DIM;

  if (ws_size < off) return;

  convert_kernel<<<(768*288 + 255)/256, 256, 0, stream>>>(
      eWhh, Wt, dWhh, dWih, encWF, wtEncF, wtDec, whhD, wihPD);
  agent_attn_kernel<<<B_TOT*T_LEN/256, 256, 0, stream>>>(x, Wa, ba, va, treprs);
  encoder_kernel<<<B_TOT/4, 512, 0, stream>>>(encWF, eWih, ebih, ebhh,
                                              treprs, eo8, h_enc);
  proj_kernel<<<B_TOT*T_LEN/64, 256, 0, stream>>>(eo8, wtEncF, ep8);
  decoder_kernel<<<B_TOT/8, 1024, 0, stream>>>(x, wtDec, bt, vt, wihPD, whhD,
                                               dbih, dbhh, Wfc, bfc, eo8, ep8,
                                               h_enc, out);
}

// Round 11
// 2147.676 us; speedup vs baseline: 2.0362x; 1.2265x over previous
//
#include <hip/hip_runtime.h>
#include <hip/hip_bf16.h>

typedef __hip_bfloat16 bf16;
typedef __attribute__((ext_vector_type(8))) short s16x8;
typedef __attribute__((ext_vector_type(4))) float f32x4;
typedef __attribute__((ext_vector_type(2))) float f32x2;

#define B_TOT 1024
#define T_LEN 256
#define H_DIM 256
#define PRED_LEN 16

__device__ __forceinline__ float b2f(short u) {
  union { unsigned int i; float f; } c;
  c.i = ((unsigned int)(unsigned short)u) << 16;
  return c.f;
}
__device__ __forceinline__ float fsig(float x) {
  return __builtin_amdgcn_rcpf(1.f + __expf(-x));
}
__device__ __forceinline__ float ftanh(float x) {
  return 1.f - 2.f * __builtin_amdgcn_rcpf(1.f + __expf(2.f * x));
}
__device__ __forceinline__ f32x4 mfma16(s16x8 a, s16x8 b, f32x4 c) {
  return __builtin_amdgcn_mfma_f32_16x16x32_bf16(a, b, c, 0, 0, 0);
}
template <int HI>
__device__ __forceinline__ f32x2 fp8pk2f(unsigned int pk) {
  return __builtin_amdgcn_cvt_pk_f32_fp8(pk, HI);
}
__device__ __forceinline__ unsigned char f2fp8(float v) {
  return (unsigned char)(__builtin_amdgcn_cvt_pk_fp8_f32(v, v, 0, 0) & 0xff);
}
__device__ __forceinline__ uint2 pk8fp8(s16x8 hv) {
  unsigned int lo = 0, hi = 0;
  lo = __builtin_amdgcn_cvt_pk_fp8_f32(b2f(hv[0]), b2f(hv[1]), lo, 0);
  lo = __builtin_amdgcn_cvt_pk_fp8_f32(b2f(hv[2]), b2f(hv[3]), lo, 1);
  hi = __builtin_amdgcn_cvt_pk_fp8_f32(b2f(hv[4]), b2f(hv[5]), hi, 0);
  hi = __builtin_amdgcn_cvt_pk_fp8_f32(b2f(hv[6]), b2f(hv[7]), hi, 1);
  uint2 w; w.x = lo; w.y = hi; return w;
}

// ---------- Kernel 0: pack fp32 weights -> bf16 ws layouts ------------------
__global__ __launch_bounds__(256) void convert_kernel(
    const float* __restrict__ eWhh, const float* __restrict__ Wt,
    const float* __restrict__ dWhh, const float* __restrict__ dWih,
    bf16* __restrict__ encWF, bf16* __restrict__ wtEncF,
    bf16* __restrict__ wtDec, bf16* __restrict__ whhD, bf16* __restrict__ wihPD)
{
  int i = blockIdx.x*256 + threadIdx.x;
  if (i < 24576) {           // encWF fragment slots
    int l = i & 63, kc = (i>>6)&7, tile = i>>9;
    int j = tile*16 + (l&15);
    int k = kc*32 + ((l>>4)&3)*8;
    #pragma unroll
    for (int e = 0; e < 8; ++e)
      encWF[i*8+e] = __float2bfloat16(eWhh[j*256 + k + e]);
  } else if (i < 32768) {    // wtEncF fragment slots
    int s = i - 24576;
    int l = s & 63, kc = (s>>6)&7, tile = s>>9;
    int j = tile*16 + (l&15);
    int k = kc*32 + ((l>>4)&3)*8;
    #pragma unroll
    for (int e = 0; e < 8; ++e)
      wtEncF[s*8+e] = __float2bfloat16(Wt[j*512 + 256 + k + e]);
  }
  if (i < 768*288) {
    int g = i / 288, k = i - g*288;
    wihPD[i] = __float2bfloat16((k < 265) ? dWih[g*265 + k] : 0.f);
  }
  if (i < 256*256) {
    int g = i >> 8, k = i & 255;
    wtDec[i] = __float2bfloat16(Wt[g*512 + k]);
  }
  if (i < 768*256) whhD[i] = __float2bfloat16(dWhh[i]);
}

// ---------- Kernel 1: agent attention (unchanged) --------------------------
__global__ __launch_bounds__(256) void agent_attn_kernel(
    const float* __restrict__ x, const float* __restrict__ Wa,
    const float* __restrict__ ba, const float* __restrict__ va,
    float* __restrict__ treprs)
{
  __shared__ float w0[256], w1[256], w2[256], baL[256], vaL[256];
  int tid = threadIdx.x;
  w0[tid] = Wa[tid*3+0];
  w1[tid] = Wa[tid*3+1];
  w2[tid] = Wa[tid*3+2];
  baL[tid] = ba[tid];
  vaL[tid] = va[tid];
  __syncthreads();
  long idx = (long)blockIdx.x * 256 + tid;
  float xa[9];
  #pragma unroll
  for (int i = 0; i < 9; ++i) xa[i] = x[idx*9 + i];
  float s0 = 0.f, s1 = 0.f, s2 = 0.f;
  for (int h = 0; h < 256; ++h) {
    float a0 = w0[h], a1 = w1[h], a2 = w2[h], bb = baL[h], vv = vaL[h];
    s0 += ftanh(a0*xa[0] + a1*xa[1] + a2*xa[2] + bb) * vv;
    s1 += ftanh(a0*xa[3] + a1*xa[4] + a2*xa[5] + bb) * vv;
    s2 += ftanh(a0*xa[6] + a1*xa[7] + a2*xa[8] + bb) * vv;
  }
  float mx = fmaxf(s0, fmaxf(s1, s2));
  float e0 = __expf(s0-mx), e1 = __expf(s1-mx), e2 = __expf(s2-mx);
  float inv = __builtin_amdgcn_rcpf(e0+e1+e2);
  e0 *= inv; e1 *= inv; e2 *= inv;
  treprs[idx*3+0] = e0*xa[0] + e1*xa[3] + e2*xa[6];
  treprs[idx*3+1] = e0*xa[1] + e1*xa[4] + e2*xa[7];
  treprs[idx*3+2] = e0*xa[2] + e1*xa[5] + e2*xa[8];
}

// ---------- Kernel 2: weight-stationary encoder (unchanged) ----------------
__global__ __launch_bounds__(512, 2) void encoder_kernel(
    const bf16* __restrict__ encWF, const float* __restrict__ eWih,
    const float* __restrict__ ebih, const float* __restrict__ ebhh,
    const float* __restrict__ treprs, unsigned char* __restrict__ eo8,
    float* __restrict__ h_enc)
{
  __shared__ __align__(16) bf16  hbF[8*64*8];
  __shared__ __align__(16) bf16  hb_lin[4*264];
  __shared__ __align__(16) float hf[4*260];
  __shared__ __align__(16) f32x4 wihAll[768];
  __shared__ float bhhnL[256];
  __shared__ float xtL[2][16];

  const int tid = threadIdx.x;
  const int b0 = blockIdx.x * 4;

  for (int i = tid; i < 768; i += 512) {
    f32x4 w;
    w.x = eWih[i*3+0]; w.y = eWih[i*3+1]; w.z = eWih[i*3+2];
    w.w = (i < 512) ? (ebih[i] + ebhh[i]) : ebih[i];
    wihAll[i] = w;
    if (i >= 512) bhhnL[i-512] = ebhh[i];
  }
  for (int i = tid; i < 4*260; i += 512) hf[i] = 0.f;
  for (int i = tid; i < 8*64*8; i += 512) hbF[i] = __float2bfloat16(0.f);
  for (int i = tid; i < 4*264; i += 512) hb_lin[i] = __float2bfloat16(0.f);
  if (tid < 16) {
    int b = tid >> 2, f = tid & 3;
    xtL[0][tid] = (f < 3) ? treprs[((long)(b0+b)*T_LEN + 0)*3 + f] : 0.f;
  }

  const int lane = tid & 63;
  const int wv   = tid >> 6;
  const int nrow = lane & 15;
  const int quad = lane >> 4;

  s16x8 wf[32];
  #pragma unroll
  for (int u = 0; u < 4; ++u) {
    int tile = (u < 2) ? (2*wv + u) : (16 + 2*wv + (u-2));
    #pragma unroll
    for (int kc = 0; kc < 8; ++kc)
      wf[u*8+kc] = *(const s16x8*)(encWF + (((long)tile*8 + kc)*64 + lane)*8);
  }
  __syncthreads();

  for (int t = 0; t < 256; ++t) {
    s16x8 afr[8];
    #pragma unroll
    for (int kc = 0; kc < 8; ++kc)
      afr[kc] = *(const s16x8*)&hbF[(kc*64 + lane)*8];
    if (t >= 1 && tid < 128) {
      int b = tid >> 5, seg = tid & 31;
      s16x8 hv = *(const s16x8*)&hb_lin[b*264 + seg*8];
      *(uint2*)(eo8 + ((long)(b0+b)*T_LEN + (t-1))*H_DIM + seg*8) = pk8fp8(hv);
    }
    __syncthreads();

    f32x4 acc[6] = {};
    #pragma unroll
    for (int kc = 0; kc < 8; ++kc) {
      #pragma unroll
      for (int u = 0; u < 4; ++u)
        acc[u] = mfma16(afr[kc], wf[u*8+kc], acc[u]);
    }
    #pragma unroll
    for (int half = 0; half < 2; ++half) {
      s16x8 nf[8];
      #pragma unroll
      for (int kc = 0; kc < 8; ++kc)
        nf[kc] = *(const s16x8*)(encWF + (((long)(32 + 2*wv + half)*8 + kc)*64 + lane)*8);
      #pragma unroll
      for (int kc = 0; kc < 8; ++kc)
        acc[4+half] = mfma16(afr[kc], nf[kc], acc[4+half]);
    }

    if (t < 255 && tid < 16) {
      int b = tid >> 2, f = tid & 3;
      xtL[(t+1)&1][tid] = (f < 3) ? treprs[((long)(b0+b)*T_LEN + (t+1))*3 + f] : 0.f;
    }

    {
      float x0 = xtL[t & 1][quad*4+0];
      float x1 = xtL[t & 1][quad*4+1];
      float x2 = xtL[t & 1][quad*4+2];
      #pragma unroll
      for (int c = 0; c < 2; ++c) {
        int j = wv*32 + c*16 + nrow;
        f32x4 wr = wihAll[j];
        f32x4 wz = wihAll[256+j];
        f32x4 wn = wihAll[512+j];
        float rg = fsig(wr.x*x0 + wr.y*x1 + wr.z*x2 + wr.w + acc[c][0]);
        float zg = fsig(wz.x*x0 + wz.y*x1 + wz.z*x2 + wz.w + acc[2+c][0]);
        float ng = ftanh(wn.x*x0 + wn.y*x1 + wn.z*x2 + wn.w
                         + rg*(acc[4+c][0] + bhhnL[j]));
        float hold = hf[quad*260 + j];
        float hnew = ng + zg*(hold - ng);
        hf[quad*260 + j] = hnew;
        bf16 hv = __float2bfloat16(hnew);
        hb_lin[quad*264 + j] = hv;
        hbF[((j>>5)*64 + ((j>>3)&3)*16 + 4*quad)*8 + (j&7)] = hv;
      }
    }
    __syncthreads();
  }

  if (tid < 128) {
    int b = tid >> 5, seg = tid & 31;
    s16x8 hv = *(const s16x8*)&hb_lin[b*264 + seg*8];
    *(uint2*)(eo8 + ((long)(b0+b)*T_LEN + 255)*H_DIM + seg*8) = pk8fp8(hv);
  }
  for (int i = tid; i < 4*256; i += 512) {
    int m = i >> 8, j = i & 255;
    h_enc[(long)(b0+m)*H_DIM + j] = hf[m*260 + j];
  }
}

// ---------- Kernel 3: enc_proj GEMM (unchanged) ----------------------------
__global__ __launch_bounds__(256) void proj_kernel(
    const unsigned char* __restrict__ eo8, const bf16* __restrict__ wtEncF,
    unsigned char* __restrict__ ep8)
{
  __shared__ __align__(16) bf16 Asm[4*8*64*8];
  __shared__ __align__(16) unsigned char Cst[64*256];
  const int tid = threadIdx.x;
  const long R0 = (long)blockIdx.x * 64;
  const int lane = tid & 63, wv = tid >> 6;
  const int nrow = lane & 15, quad = lane >> 4;

  #pragma unroll
  for (int s8 = 0; s8 < 8; ++s8) {
    int s = tid + s8*256;
    int l = s & 63, kc = (s>>6)&7, at = s>>9;
    int m = at*16 + (l&15), k = kc*32 + ((l>>4)&3)*8;
    uint2 v = *(const uint2*)(eo8 + (R0+m)*H_DIM + k);
    s16x8 o; f32x2 d;
    d = fp8pk2f<0>(v.x); o[0] = __bfloat16_as_short(__float2bfloat16(d.x)); o[1] = __bfloat16_as_short(__float2bfloat16(d.y));
    d = fp8pk2f<1>(v.x); o[2] = __bfloat16_as_short(__float2bfloat16(d.x)); o[3] = __bfloat16_as_short(__float2bfloat16(d.y));
    d = fp8pk2f<0>(v.y); o[4] = __bfloat16_as_short(__float2bfloat16(d.x)); o[5] = __bfloat16_as_short(__float2bfloat16(d.y));
    d = fp8pk2f<1>(v.y); o[6] = __bfloat16_as_short(__float2bfloat16(d.x)); o[7] = __bfloat16_as_short(__float2bfloat16(d.y));
    *(s16x8*)&Asm[s*8] = o;
  }
  __syncthreads();

  f32x4 acc[16];
  #pragma unroll
  for (int n = 0; n < 16; ++n) acc[n] = f32x4{0.f,0.f,0.f,0.f};
  #pragma unroll
  for (int kc = 0; kc < 8; ++kc) {
    s16x8 a = *(const s16x8*)&Asm[((wv*8 + kc)*64 + lane)*8];
    #pragma unroll
    for (int nt = 0; nt < 16; ++nt) {
      s16x8 b = *(const s16x8*)(wtEncF + ((nt*8 + kc)*64 + lane)*8);
      acc[nt] = mfma16(a, b, acc[nt]);
    }
  }
  #pragma unroll
  for (int nt = 0; nt < 16; ++nt)
    #pragma unroll
    for (int r = 0; r < 4; ++r)
      Cst[(wv*16 + quad*4 + r)*256 + nt*16 + nrow] = f2fp8(acc[nt][r]);
  __syncthreads();

  {
    int row = tid >> 2, seg = tid & 3;
    #pragma unroll
    for (int p = 0; p < 4; ++p)
      *(uint4*)(ep8 + (R0+row)*H_DIM + seg*64 + p*16) =
          *(const uint4*)&Cst[row*256 + seg*64 + p*16];
  }
}

// ---------- Kernel 4: decoder, 1024 thr, B_wg=4, 256 wgs (one per CU) ------
__global__ __launch_bounds__(1024) void decoder_kernel(
    const float* __restrict__ x, const bf16* __restrict__ wtDec,
    const float* __restrict__ bt, const float* __restrict__ vt,
    const bf16* __restrict__ wihPD, const bf16* __restrict__ whhD,
    const float* __restrict__ dbih, const float* __restrict__ dbhh,
    const float* __restrict__ Wfc, const float* __restrict__ bfc,
    const unsigned char* __restrict__ eo8, const unsigned char* __restrict__ ep8,
    const float* __restrict__ h_enc, float* __restrict__ out)
{
  __shared__ __align__(16) float hfL[4*260];
  __shared__ __align__(16) bf16  hbL[16*264];   // rows 4..15 stay zero
  __shared__ __align__(16) float qL[4*260];
  __shared__ float twL[4*260];
  __shared__ __align__(16) bf16  inpb[16*296];  // rows 4..15 stay zero
  __shared__ __align__(16) float vtL[256];
  __shared__ float btL[256];
  __shared__ float bsumL[512];
  __shared__ float bihnL[256];
  __shared__ float bhhnL[256];
  __shared__ __align__(16) float WfcL[9*260];
  __shared__ float bfcL[9];
  __shared__ float decin[48];
  __shared__ __align__(16) float scratch[4096];

  const int tid = threadIdx.x;
  const int b0 = blockIdx.x * 4;

  for (int i = tid; i < 256; i += 1024) {
    vtL[i] = vt[i]; btL[i] = bt[i];
    bihnL[i] = dbih[512+i]; bhhnL[i] = dbhh[512+i];
  }
  if (tid < 512) bsumL[tid] = dbih[tid] + dbhh[tid];
  for (int i = tid; i < 9*256; i += 1024) { int o = i >> 8, k = i & 255; WfcL[o*260+k] = Wfc[i]; }
  if (tid < 9) bfcL[tid] = bfc[tid];
  for (int i = tid; i < 4*260; i += 1024) { int m = i/260, j = i - m*260; hfL[i] = (j < 256) ? h_enc[(long)(b0+m)*H_DIM + j] : 0.f; }
  for (int i = tid; i < 16*264; i += 1024) {
    int m = i/264, j = i - m*264;
    hbL[i] = (m < 4 && j < 256) ? __float2bfloat16(h_enc[(long)(b0+m)*H_DIM + j])
                                : __float2bfloat16(0.f);
  }
  for (int i = tid; i < 16*296; i += 1024) inpb[i] = __float2bfloat16(0.f);
  if (tid < 36) { int b = tid/9, o = tid - b*9; decin[b*12+o] = x[((long)(b0+b)*T_LEN + (T_LEN-1))*9 + o]; }
  __syncthreads();

  const int lane = tid & 63;
  const int wv   = tid >> 6;          // 0..15
  const int nrow = lane & 15;
  const int quad = lane >> 4;
  const int jr   = wv*16 + nrow;      // this wave's gate/q column

  for (int s = 0; s < PRED_LEN; ++s) {
    // ---- phase 1: q + gh MFMAs (A = hbL) ----
    f32x4 qa = {}, ghr = {}, ghz = {}, ghn = {};
    #pragma unroll
    for (int kc = 0; kc < 8; ++kc) {
      s16x8 a = *(const s16x8*)&hbL[nrow*264 + kc*32 + quad*8];
      qa  = mfma16(a, *(const s16x8*)(wtDec + (long)jr*256 + kc*32 + quad*8), qa);
      ghr = mfma16(a, *(const s16x8*)(whhD + (long)jr*256 + kc*32 + quad*8), ghr);
      ghz = mfma16(a, *(const s16x8*)(whhD + (long)(256+jr)*256 + kc*32 + quad*8), ghz);
      ghn = mfma16(a, *(const s16x8*)(whhD + (long)(512+jr)*256 + kc*32 + quad*8), ghn);
    }
    if (quad == 0) {
      #pragma unroll
      for (int r = 0; r < 4; ++r)
        qL[r*260 + jr] = qa[r] + btL[jr];
    }
    __syncthreads();

    // ---- phase 2: scores (thread = (b, t), 1024 = 4x256) ----
    {
      int bb = tid >> 8, t = tid & 255;
      const float* qrow = &qL[bb*260];
      const uint4* ep4 = (const uint4*)(ep8 + ((long)(b0+bb)*T_LEN + t)*H_DIM);
      float s0 = 0.f, s1 = 0.f;
      #pragma unroll 2
      for (int kc = 0; kc < 16; ++kc) {
        uint4 pv = ep4[kc];
        int k = kc*16;
        f32x2 d;
        d = fp8pk2f<0>(pv.x); s0 += ftanh(d.x + qrow[k+0])*vtL[k+0];  s1 += ftanh(d.y + qrow[k+1])*vtL[k+1];
        d = fp8pk2f<1>(pv.x); s0 += ftanh(d.x + qrow[k+2])*vtL[k+2];  s1 += ftanh(d.y + qrow[k+3])*vtL[k+3];
        d = fp8pk2f<0>(pv.y); s0 += ftanh(d.x + qrow[k+4])*vtL[k+4];  s1 += ftanh(d.y + qrow[k+5])*vtL[k+5];
        d = fp8pk2f<1>(pv.y); s0 += ftanh(d.x + qrow[k+6])*vtL[k+6];  s1 += ftanh(d.y + qrow[k+7])*vtL[k+7];
        d = fp8pk2f<0>(pv.z); s0 += ftanh(d.x + qrow[k+8])*vtL[k+8];  s1 += ftanh(d.y + qrow[k+9])*vtL[k+9];
        d = fp8pk2f<1>(pv.z); s0 += ftanh(d.x + qrow[k+10])*vtL[k+10]; s1 += ftanh(d.y + qrow[k+11])*vtL[k+11];
        d = fp8pk2f<0>(pv.w); s0 += ftanh(d.x + qrow[k+12])*vtL[k+12]; s1 += ftanh(d.y + qrow[k+13])*vtL[k+13];
        d = fp8pk2f<1>(pv.w); s0 += ftanh(d.x + qrow[k+14])*vtL[k+14]; s1 += ftanh(d.y + qrow[k+15])*vtL[k+15];
      }
      scratch[bb*256 + t] = s0 + s1;
    }
    __syncthreads();

    // ---- phase 2b: softmax (wave b handles batch row b) ----
    if (wv < 4) {
      float v4[4];
      float mx = -1e30f;
      #pragma unroll
      for (int i = 0; i < 4; ++i) { v4[i] = scratch[wv*256 + lane + 64*i]; mx = fmaxf(mx, v4[i]); }
      #pragma unroll
      for (int off = 1; off < 64; off <<= 1) mx = fmaxf(mx, __shfl_xor(mx, off));
      float sum = 0.f;
      #pragma unroll
      for (int i = 0; i < 4; ++i) { v4[i] = __expf(v4[i] - mx); sum += v4[i]; }
      #pragma unroll
      for (int off = 1; off < 64; off <<= 1) sum += __shfl_xor(sum, off);
      float inv = __builtin_amdgcn_rcpf(sum);
      #pragma unroll
      for (int i = 0; i < 4; ++i) twL[wv*260 + lane + 64*i] = v4[i] * inv;
    }
    __syncthreads();

    // ---- phase 2c: context partials (tq of 4, b of 4, 64 h-chunks of 4) ----
    {
      int tq = tid >> 8, rem = tid & 255;
      int b = rem >> 6, hc = (rem & 63) * 4;
      const unsigned char* eob = eo8 + ((long)(b0+b)*T_LEN + tq*64)*H_DIM + hc;
      const float* tw = &twL[b*260 + tq*64];
      float c0 = 0.f, c1 = 0.f, c2 = 0.f, c3 = 0.f;
      #pragma unroll 4
      for (int t = 0; t < 64; ++t) {
        unsigned int ev = *(const unsigned int*)(eob + (long)t*H_DIM);
        float w = tw[t];
        f32x2 d0 = fp8pk2f<0>(ev);
        f32x2 d1 = fp8pk2f<1>(ev);
        c0 += w*d0.x; c1 += w*d0.y; c2 += w*d1.x; c3 += w*d1.y;
      }
      scratch[tq*1024 + b*256 + hc + 0] = c0;
      scratch[tq*1024 + b*256 + hc + 1] = c1;
      scratch[tq*1024 + b*256 + hc + 2] = c2;
      scratch[tq*1024 + b*256 + hc + 3] = c3;
    }
    __syncthreads();
    // ---- phase 2d: reduce -> inpb ----
    {
      int b = tid >> 8, h = tid & 255;
      float sum = scratch[tid] + scratch[1024 + tid]
                + scratch[2048 + tid] + scratch[3072 + tid];
      inpb[b*296 + 9 + h] = __float2bfloat16(sum);
      if (tid < 36) { int bb = tid/9, o = tid - bb*9; inpb[bb*296 + o] = __float2bfloat16(decin[bb*12 + o]); }
    }
    __syncthreads();

    // ---- phase 3: gi MFMAs (A = inpb) + combine ----
    {
      f32x4 gir = {}, giz = {}, gin = {};
      #pragma unroll
      for (int kc = 0; kc < 9; ++kc) {
        s16x8 a = *(const s16x8*)&inpb[nrow*296 + kc*32 + quad*8];
        gir = mfma16(a, *(const s16x8*)(wihPD + (long)jr*288 + kc*32 + quad*8), gir);
        giz = mfma16(a, *(const s16x8*)(wihPD + (long)(256+jr)*288 + kc*32 + quad*8), giz);
        gin = mfma16(a, *(const s16x8*)(wihPD + (long)(512+jr)*288 + kc*32 + quad*8), gin);
      }
      if (quad == 0) {
        #pragma unroll
        for (int r = 0; r < 4; ++r) {
          float rg = fsig(gir[r] + ghr[r] + bsumL[jr]);
          float zg = fsig(giz[r] + ghz[r] + bsumL[256+jr]);
          float ng = ftanh(gin[r] + bihnL[jr] + rg*(ghn[r] + bhhnL[jr]));
          float hold = hfL[r*260 + jr];
          float hnew = ng + zg*(hold - ng);
          hfL[r*260 + jr] = hnew;
          hbL[r*264 + jr] = __float2bfloat16(hnew);
        }
      }
    }
    __syncthreads();

    // ---- phase 4: pred = h_new @ Wfc^T + bfc ----
    if (tid < 288) {
      int b = tid / 72, rem = tid - b*72;
      int o = rem >> 3, ch = rem & 7;
      float ps = 0.f;
      #pragma unroll
      for (int k = ch*32; k < ch*32 + 32; ++k)
        ps += hfL[b*260 + k] * WfcL[o*260 + k];
      scratch[tid] = ps;
    }
    __syncthreads();
    if (tid < 36) {
      int b = tid / 9, o = tid - b*9;
      float sum = bfcL[o];
      #pragma unroll
      for (int ch = 0; ch < 8; ++ch) sum += scratch[b*72 + o*8 + ch];
      out[((long)(b0+b)*PRED_LEN + s)*9 + o] = sum;
      decin[b*12 + o] = sum;
    }
    __syncthreads();
  }
}

extern "C" void kernel_launch(void* const* d_in, const int* in_sizes, int n_in,
                              void* d_out, int out_size, void* d_ws, size_t ws_size,
                              hipStream_t stream)
{
  const float* x    = (const float*)d_in[0];
  const float* Wa   = (const float*)d_in[1];
  const float* ba   = (const float*)d_in[2];
  const float* va   = (const float*)d_in[3];
  const float* eWih = (const float*)d_in[4];
  const float* eWhh = (const float*)d_in[5];
  const float* ebih = (const float*)d_in[6];
  const float* ebhh = (const float*)d_in[7];
  const float* dWih = (const float*)d_in[8];
  const float* dWhh = (const float*)d_in[9];
  const float* dbih = (const float*)d_in[10];
  const float* dbhh = (const float*)d_in[11];
  const float* Wt   = (const float*)d_in[12];
  const float* bt   = (const float*)d_in[13];
  const float* vt   = (const float*)d_in[14];
  const float* Wfc  = (const float*)d_in[15];
  const float* bfc  = (const float*)d_in[16];
  float* out = (float*)d_out;

  char* ws = (char*)d_ws;
  size_t off = 0;
  bf16* encWF   = (bf16*)(ws + off); off += (size_t)48*8*64*8*sizeof(bf16);
  bf16* wtEncF  = (bf16*)(ws + off); off += (size_t)16*8*64*8*sizeof(bf16);
  bf16* wtDec   = (bf16*)(ws + off); off += (size_t)256*256*sizeof(bf16);
  bf16* whhD    = (bf16*)(ws + off); off += (size_t)768*256*sizeof(bf16);
  bf16* wihPD   = (bf16*)(ws + off); off += (size_t)768*288*sizeof(bf16);
  float* treprs = (float*)(ws + off); off += (size_t)B_TOT*T_LEN*3*sizeof(float);
  float* h_enc  = (float*)(ws + off); off += (size_t)B_TOT*H_DIM*sizeof(float);
  unsigned char* eo8 = (unsigned char*)(ws + off); off += (size_t)B_TOT*T_LEN*H_DIM;
  unsigned char* ep8 = (unsigned char*)(ws + off); off += (size_t)B_TOT*T_LEN*H_DIM;

  if (ws_size < off) return;

  convert_kernel<<<(768*288 + 255)/256, 256, 0, stream>>>(
      eWhh, Wt, dWhh, dWih, encWF, wtEncF, wtDec, whhD, wihPD);
  agent_attn_kernel<<<B_TOT*T_LEN/256, 256, 0, stream>>>(x, Wa, ba, va, treprs);
  encoder_kernel<<<B_TOT/4, 512, 0, stream>>>(encWF, eWih, ebih, ebhh,
                                              treprs, eo8, h_enc);
  proj_kernel<<<B_TOT*T_LEN/64, 256, 0, stream>>>(eo8, wtEncF, ep8);
  decoder_kernel<<<B_TOT/4, 1024, 0, stream>>>(x, wtDec, bt, vt, wihPD, whhD,
                                               dbih, dbhh, Wfc, bfc, eo8, ep8,
                                               h_enc, out);
}